// Round 7
// baseline (1565.664 us; speedup 1.0000x reference)
//
#include <hip/hip_runtime.h>

typedef _Float16 f16x8 __attribute__((ext_vector_type(8)));
typedef float    f32x4 __attribute__((ext_vector_type(4)));
typedef float    f32x2 __attribute__((ext_vector_type(2)));
typedef short    bf16x8 __attribute__((ext_vector_type(8)));

__device__ __forceinline__ float b2f(ushort u){
  union { float f; unsigned int i; } v; v.i = ((unsigned int)u) << 16; return v.f;
}
__device__ __forceinline__ ushort f2b(float f){
  union { float f; unsigned int i; } v; v.f = f;
  unsigned int r = (v.i + 0x7FFFu + ((v.i >> 16) & 1u)) >> 16;
  return (ushort)r;
}
__device__ __forceinline__ ushort f2h_u(float f){
  union { _Float16 h; ushort u; } v; v.h = (_Float16)f; return v.u;
}
// flag-typed load: f=1 -> fp32 array, f=0 -> bf16(ushort) array
__device__ __forceinline__ float ldf(const void* p, size_t i, int f){
  return f ? ((const float*)p)[i] : b2f(((const ushort*)p)[i]);
}
// async global->LDS, 16B per lane; LDS dest must be wave-uniform base (+lane*16)
__device__ __forceinline__ void gld16(const void* g, void* l)
{
  __builtin_amdgcn_global_load_lds(
      (const __attribute__((address_space(1))) void*)g,
      (__attribute__((address_space(3))) void*)l, 16, 0, 0);
}

// ---------------------------------------------------------------------------
// Input storage detector on x: packed bf16 -> 0 ; fp32 (any) -> 1.
// ---------------------------------------------------------------------------
__global__ void detect_k(const void* __restrict__ x, int* __restrict__ flag)
{
  const int lane = threadIdx.x; // 64
  const ushort* p = (const ushort*)x;
  int wild = 0, zeven = 0;
#pragma unroll
  for (int j = 0; j < 8; ++j) {
    const int idx = lane * 8 + j;
    const ushort u = p[idx];
    if (((u >> 7) & 0xFF) >= 0xF1) ++wild;
    if (((idx & 1) == 0) && u == 0) ++zeven;
  }
#pragma unroll
  for (int off = 1; off < 64; off <<= 1) {
    wild += __shfl_xor(wild, off);
    zeven += __shfl_xor(zeven, off);
  }
  if (lane == 0) *flag = (wild >= 4 || zeven >= 128) ? 1 : 0;
}

// W table: logits = sq*sk * sum_d wt[d]*q_d*k_d  with 1/8 folded in.
// Also zeroes the overflow-row counter each launch.
__global__ void wtab_k(float* __restrict__ w, int* __restrict__ zeroc,
                       unsigned* __restrict__ ovc)
{
  const int d = threadIdx.x; // 64
  const int i = (d >> 1) & 15;
  const double F2 = pow(10000.0, -(double)i / 8.0);
  const double G2 = pow(10000.0, -(double)(2 * i + 1) / 16.0);
  w[d] = (float)((F2 + G2) * 0.125);
  if (d == 0) { *zeroc = 0; *ovc = 0u; }
}

// ---------------------------------------------------------------------------
// Weight convert + transpose: W[K][N] (flag-typed) -> Wt[N][K] f16.
// ---------------------------------------------------------------------------
__global__ __launch_bounds__(256) void cvt_wT_k(const void* __restrict__ W,
    const int* __restrict__ fp, _Float16* __restrict__ Wt, int K, int N)
{
  __shared__ float t[32][33];
  const int f = *fp;
  const int n0 = blockIdx.x * 32, k0 = blockIdx.y * 32;
  const int ln = threadIdx.x & 31, lr = threadIdx.x >> 5;
#pragma unroll
  for (int u = 0; u < 4; ++u) {
    const int kk = lr + u * 8;
    t[kk][ln] = ldf(W, (size_t)(k0 + kk) * N + n0 + ln, f);
  }
  __syncthreads();
#pragma unroll
  for (int u = 0; u < 4; ++u) {
    const int nn = lr + u * 8;
    Wt[(size_t)(n0 + nn) * K + k0 + ln] = (_Float16)t[ln][nn];
  }
}

// ---------------------------------------------------------------------------
// fp32 VALU GEMM, 128x128 tile, 8x8 per thread. QKV scatter modes only.
// (unchanged -- bit-identical q/k/v)
// ---------------------------------------------------------------------------
template<int MODE>
__global__ __launch_bounds__(256) void sgemm2(
    const void* __restrict__ A, const int* __restrict__ afp,
    const void* __restrict__ W, const void* __restrict__ bias,
    const int* __restrict__ wfp,
    ushort* __restrict__ outU, float* __restrict__ outF,
    const float* __restrict__ wtab,
    int N, int K)
{
  __shared__ float As[16][128];   // [kk][row] (transposed on store)
  __shared__ float Ws[16][132];   // [kk][col] padded
  const int tid = threadIdx.x;
  const int tx = tid & 15, ty = tid >> 4;
  const int bn = blockIdx.x * 128, bm = blockIdx.y * 128;
  const int af = *afp, wf = *wfp;

  float acc[8][8] = {};

  for (int k0 = 0; k0 < K; k0 += 16) {
    __syncthreads();
    {   // stage A: 128 rows x 16 k, transposed into As[kk][row]
      const int row = tid >> 1, kk0 = (tid & 1) * 8;
      float tmp[8];
      if (af) {
        const float4* p = (const float4*)((const float*)A + (size_t)(bm + row) * K + k0 + kk0);
        const float4 a = p[0], b = p[1];
        tmp[0]=a.x; tmp[1]=a.y; tmp[2]=a.z; tmp[3]=a.w;
        tmp[4]=b.x; tmp[5]=b.y; tmp[6]=b.z; tmp[7]=b.w;
      } else {
        const uint4 u = *(const uint4*)((const ushort*)A + (size_t)(bm + row) * K + k0 + kk0);
        tmp[0]=b2f((ushort)(u.x&0xffff)); tmp[1]=b2f((ushort)(u.x>>16));
        tmp[2]=b2f((ushort)(u.y&0xffff)); tmp[3]=b2f((ushort)(u.y>>16));
        tmp[4]=b2f((ushort)(u.z&0xffff)); tmp[5]=b2f((ushort)(u.z>>16));
        tmp[6]=b2f((ushort)(u.w&0xffff)); tmp[7]=b2f((ushort)(u.w>>16));
      }
#pragma unroll
      for (int u = 0; u < 8; ++u) As[kk0 + u][row] = tmp[u];
    }
    {   // stage W: 16 k x 128 cols
      const int kk = tid >> 4, c0 = (tid & 15) * 8;
      float tmp[8];
      if (wf) {
        const float4* p = (const float4*)((const float*)W + (size_t)(k0 + kk) * N + bn + c0);
        const float4 a = p[0], b = p[1];
        tmp[0]=a.x; tmp[1]=a.y; tmp[2]=a.z; tmp[3]=a.w;
        tmp[4]=b.x; tmp[5]=b.y; tmp[6]=b.z; tmp[7]=b.w;
      } else {
        const uint4 u = *(const uint4*)((const ushort*)W + (size_t)(k0 + kk) * N + bn + c0);
        tmp[0]=b2f((ushort)(u.x&0xffff)); tmp[1]=b2f((ushort)(u.x>>16));
        tmp[2]=b2f((ushort)(u.y&0xffff)); tmp[3]=b2f((ushort)(u.y>>16));
        tmp[4]=b2f((ushort)(u.z&0xffff)); tmp[5]=b2f((ushort)(u.z>>16));
        tmp[6]=b2f((ushort)(u.w&0xffff)); tmp[7]=b2f((ushort)(u.w>>16));
      }
      *(float4*)&Ws[kk][c0]     = make_float4(tmp[0], tmp[1], tmp[2], tmp[3]);
      *(float4*)&Ws[kk][c0 + 4] = make_float4(tmp[4], tmp[5], tmp[6], tmp[7]);
    }
    __syncthreads();
#pragma unroll
    for (int kk = 0; kk < 16; ++kk) {
      float ar[8], wr[8];
      const float4 a0 = *(const float4*)&As[kk][ty * 8];
      const float4 a1 = *(const float4*)&As[kk][ty * 8 + 4];
      ar[0]=a0.x; ar[1]=a0.y; ar[2]=a0.z; ar[3]=a0.w;
      ar[4]=a1.x; ar[5]=a1.y; ar[6]=a1.z; ar[7]=a1.w;
      const float4 w0 = *(const float4*)&Ws[kk][tx * 8];
      const float4 w1 = *(const float4*)&Ws[kk][tx * 8 + 4];
      wr[0]=w0.x; wr[1]=w0.y; wr[2]=w0.z; wr[3]=w0.w;
      wr[4]=w1.x; wr[5]=w1.y; wr[6]=w1.z; wr[7]=w1.w;
#pragma unroll
      for (int i = 0; i < 8; ++i)
#pragma unroll
        for (int j = 0; j < 8; ++j) acc[i][j] += ar[i] * wr[j];
    }
  }

#pragma unroll
  for (int i = 0; i < 8; ++i) {
    const int gr = bm + ty * 8 + i;
    const int b = gr >> 11, s = gr & 2047;
#pragma unroll
    for (int j = 0; j < 8; ++j) {
      const int gc = bn + tx * 8 + j;
      float v = acc[i][j] + ldf(bias, gc, wf);
      const int hh = gc >> 6, dh = gc & 63;
      const size_t idx = (size_t)b * 2097152 + (((size_t)hh * 2048) + s) * 64 + dh;
      if (MODE == 0)      outF[idx] = v * wtab[dh];
      else if (MODE == 1) outF[idx] = v;
      else                outU[idx] = f2b(v);
    }
  }
}

// ---------------------------------------------------------------------------
// fp32 VALU GEMM (fallback path, unchanged).
// ---------------------------------------------------------------------------
template<int MODE>
__global__ __launch_bounds__(256) void sgemm(
    const void* __restrict__ A, const int* __restrict__ afp, int arow0,
    const void* __restrict__ W, const void* __restrict__ bias,
    const int* __restrict__ wfp,
    const void* __restrict__ res, const int* __restrict__ rfp,
    ushort* __restrict__ outU, float* __restrict__ outF,
    const float* __restrict__ wtab,
    int N, int K, int erow0)
{
  __shared__ float As[64][17];
  __shared__ float Ws[16][65];
  const int tid = threadIdx.x;
  const int tx = tid & 15, ty = tid >> 4;
  const int bn = blockIdx.x * 64, bm = blockIdx.y * 64;
  const int af = *afp, wf = *wfp;

  float acc[4][4] = {};

  for (int k0 = 0; k0 < K; k0 += 16) {
    __syncthreads();
#pragma unroll
    for (int u = 0; u < 4; ++u) {
      const int idx = tid * 4 + u;
      const int row = idx >> 4, kk = idx & 15;
      As[row][kk] = ldf(A, (size_t)(arow0 + bm + row) * K + k0 + kk, af);
    }
#pragma unroll
    for (int u = 0; u < 4; ++u) {
      const int idx = tid * 4 + u;
      const int kk = idx >> 6, col = idx & 63;
      Ws[kk][col] = ldf(W, (size_t)(k0 + kk) * N + bn + col, wf);
    }
    __syncthreads();
#pragma unroll
    for (int kk = 0; kk < 16; ++kk) {
      float ar[4], wr[4];
#pragma unroll
      for (int i = 0; i < 4; ++i) ar[i] = As[ty * 4 + i][kk];
#pragma unroll
      for (int j = 0; j < 4; ++j) wr[j] = Ws[kk][tx * 4 + j];
#pragma unroll
      for (int i = 0; i < 4; ++i)
#pragma unroll
        for (int j = 0; j < 4; ++j) acc[i][j] += ar[i] * wr[j];
    }
  }

  const int rf = (MODE >= 4) ? *rfp : 0;
#pragma unroll
  for (int i = 0; i < 4; ++i) {
    const int gr = erow0 + bm + ty * 4 + i;
#pragma unroll
    for (int j = 0; j < 4; ++j) {
      const int gc = bn + tx * 4 + j;
      float v = acc[i][j] + ldf(bias, gc, wf);
      if (MODE == 0) {
        const int hh = gc >> 6, dh = gc & 63, s = gr & 2047;
        outF[(((size_t)hh * 2048) + s) * 64 + dh] = v * wtab[dh];
      } else if (MODE == 1) {
        const int hh = gc >> 6, dh = gc & 63, s = gr & 2047;
        outF[(((size_t)hh * 2048) + s) * 64 + dh] = v;
      } else if (MODE == 2) {
        const int hh = gc >> 6, dh = gc & 63, s = gr & 2047;
        outU[(((size_t)hh * 2048) + s) * 64 + dh] = f2b(v);
      } else if (MODE == 3) {
        outU[(size_t)gr * N + gc] = f2b(fmaxf(v, 0.f));
      } else if (MODE == 4) {
        v += ldf(res, (size_t)gr * 1024 + gc, rf);
        outU[(size_t)gr * 1024 + gc] = f2b(v);
      } else {
        v += ldf(res, (size_t)gr * 1024 + gc, rf);
        outF[(size_t)gr * 1024 + gc] = v;
      }
    }
  }
}

// ---------------------------------------------------------------------------
// f16 MFMA GEMM, 2-phase double-buffered pipeline: prefetch tile k+1's
// global_load_lds BEFORE the ds_read+MFMA phase of tile k; single barrier
// per K-step drains loads that overlapped the MFMA phase. Bytes moved and
// arithmetic identical to the single-buffered version -> bit-identical.
// ---------------------------------------------------------------------------
template<int MODE, int TM>
__global__ __launch_bounds__(256) void hgemm(
    const _Float16* __restrict__ A, int arow0,
    const _Float16* __restrict__ Wt,
    const void* __restrict__ bias, const int* __restrict__ bfp,
    const void* __restrict__ res, const int* __restrict__ rfp,
    const _Float16* __restrict__ resH,
    _Float16* __restrict__ outH, float* __restrict__ outF,
    int N, int K, int erow0)
{
  constexpr int MF = TM / 32;
  __shared__ _Float16 As[2][TM][32];
  __shared__ _Float16 Bs[2][128][32];
  const int tid = threadIdx.x;
  const int lane = tid & 63;
  const int w = tid >> 6;
  const int wm = w >> 1, wn = w & 1;
  const int fr = lane & 15, g = lane >> 4;
  const int bn = blockIdx.x * 128, bm = blockIdx.y * TM;

  f32x4 acc[MF][4];
#pragma unroll
  for (int m = 0; m < MF; ++m)
#pragma unroll
    for (int n = 0; n < 4; ++n)
      acc[m][n][0] = acc[m][n][1] = acc[m][n][2] = acc[m][n][3] = 0.f;

  auto STAGE = [&](int buf, int k0) {
    if constexpr (TM == 128) {
#pragma unroll
      for (int i = 0; i < 2; ++i) {
        const int c = (w * 2 + i) * 64 + lane;
        gld16(A + (size_t)(arow0 + bm + (c >> 2)) * K + k0 + (c & 3) * 8,
              (char*)As[buf] + (w * 2 + i) * 1024);
      }
    } else {
      const int c = w * 64 + lane;
      gld16(A + (size_t)(arow0 + bm + (c >> 2)) * K + k0 + (c & 3) * 8,
            (char*)As[buf] + w * 1024);
    }
#pragma unroll
    for (int i = 0; i < 2; ++i) {
      const int c = (w * 2 + i) * 64 + lane;
      gld16(Wt + (size_t)(bn + (c >> 2)) * K + k0 + (c & 3) * 8,
            (char*)Bs[buf] + (w * 2 + i) * 1024);
    }
  };

  STAGE(0, 0);
  __syncthreads();               // drains vmcnt(0): buf0 ready
  int cur = 0;
  for (int k0 = 0; k0 < K; k0 += 32) {
    if (k0 + 32 < K) STAGE(cur ^ 1, k0 + 32);   // async: flies during MFMA
    f16x8 afr[MF], bf8[4];
#pragma unroll
    for (int m = 0; m < MF; ++m)
      afr[m] = *(const f16x8*)&As[cur][wm * (TM / 2) + m * 16 + fr][g * 8];
#pragma unroll
    for (int n = 0; n < 4; ++n)
      bf8[n] = *(const f16x8*)&Bs[cur][wn * 64 + n * 16 + fr][g * 8];
#pragma unroll
    for (int m = 0; m < MF; ++m)
#pragma unroll
      for (int n = 0; n < 4; ++n)
        acc[m][n] = __builtin_amdgcn_mfma_f32_16x16x32_f16(afr[m], bf8[n], acc[m][n], 0, 0, 0);
    __syncthreads();             // prefetch landed (overlapped) + buffer-swap guard
    cur ^= 1;
  }

  const int bfl = *bfp;
  const int rfl = (MODE == 4) ? *rfp : 0;
#pragma unroll
  for (int m = 0; m < MF; ++m) {
#pragma unroll
    for (int n = 0; n < 4; ++n) {
      const int gc = bn + wn * 64 + n * 16 + fr;
      const float bv = ldf(bias, gc, bfl);
#pragma unroll
      for (int e = 0; e < 4; ++e) {
        const int gr = erow0 + bm + wm * (TM / 2) + m * 16 + (lane >> 4) * 4 + e;
        float v = acc[m][n][e] + bv;
        if (MODE == 3) {
          outH[(size_t)gr * N + gc] = (_Float16)fmaxf(v, 0.f);
        } else if (MODE == 4) {
          v += ldf(res, (size_t)gr * 1024 + gc, rfl);
          outH[(size_t)gr * 1024 + gc] = (_Float16)v;
        } else {
          v += (float)resH[(size_t)gr * 1024 + gc];
          outF[(size_t)gr * 1024 + gc] = v;
        }
      }
    }
  }
}

// ---------------------------------------------------------------------------
// MFMA attention, single pass, 128 q-rows per block (2 row-fragment sets per
// wave) -- halves the per-row cost of the 3-way bf16 K-splitting, which was
// the dominant VALU load. Arithmetic per row identical to the 64-row version.
// Q staged in two 64-row passes reusing the transient LDS area.
// ---------------------------------------------------------------------------
#define ACAP 48

__global__ __launch_bounds__(256) void attn_mfma_k(
    const float* __restrict__ qb, const float* __restrict__ kb,
    const ushort* __restrict__ vb, ushort* __restrict__ ctx,
    unsigned* __restrict__ ovcount, unsigned* __restrict__ ovlist)
{
  __shared__ __align__(16) char smem[51712];
  ushort*   kpl  = (ushort*)smem;                 // [3][32][72] bf16 bits, 13824 B
  unsigned* cnt  = (unsigned*)(smem + 13824);     // [128]
  float*    mrow = (float*)(smem + 14336);        // [128]
  ushort*   cL   = (ushort*)(smem + 14848);       // [128][ACAP] 12288 B
  float*    LL   = (float*)(smem + 27136);        // [128][ACAP] 24576 B (end 51712)

  const int tid  = threadIdx.x;
  const int lane = tid & 63;
  const int wv   = tid >> 6;
  const int fr   = lane & 15, g = lane >> 4;
  const int h = blockIdx.y, b = blockIdx.z;
  const int s0 = blockIdx.x * 128;
  const size_t bh = (size_t)b * 16 + h;
  const float*  qh = qb + bh * (2048 * 64);
  const float*  kh = kb + bh * (2048 * 64);
  const ushort* vh = vb + bh * (2048 * 64);

  // ---- stage Q (128 rows x 64 dims) as 3 bf16 planes, two 64-row passes ----
  bf16x8 af[2][3][2];           // [row-set][plane][dg]
#pragma unroll
  for (int rs = 0; rs < 2; ++rs) {
    if (rs) __syncthreads();    // pass-A extraction done before overwrite
    {
      ushort* qs = (ushort*)smem;   // [3][64][72], plane stride 4608 elems
      const int r = tid >> 2, d0 = (tid & 3) * 16;
      const float4* qp = (const float4*)(qh + (size_t)(s0 + rs * 64 + r) * 64 + d0);
      float tv[16];
#pragma unroll
      for (int u = 0; u < 4; ++u) {
        const float4 t = qp[u];
        tv[u*4]=t.x; tv[u*4+1]=t.y; tv[u*4+2]=t.z; tv[u*4+3]=t.w;
      }
      ushort p0[16], p1[16], p2[16];
#pragma unroll
      for (int u = 0; u < 16; ++u) {
        const float v = tv[u];
        const ushort a0 = f2b(v);
        const float r1 = v - b2f(a0);
        const ushort a1 = f2b(r1);
        const float r2 = r1 - b2f(a1);
        p0[u]=a0; p1[u]=a1; p2[u]=f2b(r2);
      }
      const int base = r * 72 + d0;
#pragma unroll
      for (int u = 0; u < 2; ++u) {
        *(uint4*)&((ushort*)smem)[0*4608 + base + u*8] = *(uint4*)&p0[u*8];
        *(uint4*)&((ushort*)smem)[1*4608 + base + u*8] = *(uint4*)&p1[u*8];
        *(uint4*)&((ushort*)smem)[2*4608 + base + u*8] = *(uint4*)&p2[u*8];
      }
    }
    __syncthreads();
    {
      ushort* qs = (ushort*)smem;
      const int rb = (wv * 16 + fr) * 72 + g * 8;
#pragma unroll
      for (int p = 0; p < 3; ++p)
#pragma unroll
        for (int dg = 0; dg < 2; ++dg)
          af[rs][p][dg] = *(bf16x8*)&qs[p*4608 + rb + dg*32];
    }
  }
  __syncthreads();
  if (tid < 128) cnt[tid] = 0;

  float svv[2][4];
#pragma unroll
  for (int rs = 0; rs < 2; ++rs)
#pragma unroll
    for (int e = 0; e < 4; ++e)
      svv[rs][e] = (float)(s0 + rs * 64 + wv * 16 + g * 4 + e);

  float mloc[2][4];
#pragma unroll
  for (int rs = 0; rs < 2; ++rs)
#pragma unroll
    for (int e = 0; e < 4; ++e) mloc[rs][e] = -3.0e38f;

  // -------- single pass: L, online row max, candidate collection --------
  for (int c0 = 0; c0 < 2048; c0 += 32) {
    __syncthreads();
    {   // stage 32 keys x 64 dims as 3 bf16 planes (once per tile)
      const int key = tid >> 3, d0 = (tid & 7) * 8;
      const float4* kp4 = (const float4*)(kh + (size_t)(c0 + key) * 64 + d0);
      const float4 t0 = kp4[0], t1 = kp4[1];
      float tv[8] = {t0.x,t0.y,t0.z,t0.w,t1.x,t1.y,t1.z,t1.w};
      ushort p0[8], p1[8], p2[8];
#pragma unroll
      for (int u = 0; u < 8; ++u) {
        const float v = tv[u];
        const ushort a0 = f2b(v);
        const float r1 = v - b2f(a0);
        const ushort a1 = f2b(r1);
        const float r2 = r1 - b2f(a1);
        p0[u]=a0; p1[u]=a1; p2[u]=f2b(r2);
      }
      const int base = key * 72 + d0;
      *(uint4*)&kpl[0*2304 + base] = *(uint4*)&p0[0];
      *(uint4*)&kpl[1*2304 + base] = *(uint4*)&p1[0];
      *(uint4*)&kpl[2*2304 + base] = *(uint4*)&p2[0];
    }
    __syncthreads();

    float Lv[2][2][4];
#pragma unroll
    for (int rs = 0; rs < 2; ++rs) {
#pragma unroll
      for (int kg = 0; kg < 2; ++kg) {
        f32x4 a0v = {0.f,0.f,0.f,0.f}, a1v = {0.f,0.f,0.f,0.f}, a2v = {0.f,0.f,0.f,0.f};
#pragma unroll
        for (int dg = 0; dg < 2; ++dg) {
          const int rb = (kg * 16 + fr) * 72 + dg * 32 + g * 8;
          const bf16x8 b0 = *(bf16x8*)&kpl[0*2304 + rb];
          const bf16x8 b1 = *(bf16x8*)&kpl[1*2304 + rb];
          const bf16x8 b2 = *(bf16x8*)&kpl[2*2304 + rb];
          a0v = __builtin_amdgcn_mfma_f32_16x16x32_bf16(af[rs][0][dg], b0, a0v, 0,0,0);
          a1v = __builtin_amdgcn_mfma_f32_16x16x32_bf16(af[rs][0][dg], b1, a1v, 0,0,0);
          a2v = __builtin_amdgcn_mfma_f32_16x16x32_bf16(af[rs][1][dg], b0, a2v, 0,0,0);
          a0v = __builtin_amdgcn_mfma_f32_16x16x32_bf16(af[rs][1][dg], b1, a0v, 0,0,0);
          a1v = __builtin_amdgcn_mfma_f32_16x16x32_bf16(af[rs][0][dg], b2, a1v, 0,0,0);
          a2v = __builtin_amdgcn_mfma_f32_16x16x32_bf16(af[rs][2][dg], b0, a2v, 0,0,0);
        }
        const float cw = (float)(c0 + kg * 16 + fr);
#pragma unroll
        for (int e = 0; e < 4; ++e) {
          const float a = (a0v[e] + a1v[e]) + a2v[e];
          Lv[rs][kg][e] = a * cw * svv[rs][e];
        }
      }
      // per-row tile max across the 16 fr-lanes; update running max (uniform)
#pragma unroll
      for (int e = 0; e < 4; ++e) {
        float t = fmaxf(Lv[rs][0][e], Lv[rs][1][e]);
#pragma unroll
        for (int off = 1; off < 16; off <<= 1) t = fmaxf(t, __shfl_xor(t, off));
        mloc[rs][e] = fmaxf(mloc[rs][e], t);
      }
      // collect candidates vs the current running max
#pragma unroll
      for (int kg = 0; kg < 2; ++kg)
#pragma unroll
        for (int e = 0; e < 4; ++e) {
          if (Lv[rs][kg][e] > mloc[rs][e] - 80.f) {
            const int row = rs * 64 + wv * 16 + g * 4 + e;
            const unsigned idx = atomicAdd(&cnt[row], 1u);
            if (idx < ACAP) {
              cL[row * ACAP + idx] = (ushort)(c0 + kg * 16 + fr);
              LL[row * ACAP + idx] = Lv[rs][kg][e];
            }
          }
        }
    }
  }
  // final row max (uniform across the 16 fr-lanes)
  if (fr == 0) {
#pragma unroll
    for (int rs = 0; rs < 2; ++rs)
#pragma unroll
      for (int e = 0; e < 4; ++e)
        mrow[rs * 64 + wv * 16 + g * 4 + e] = mloc[rs][e];
  }
  __syncthreads();

  // -------- phase 3: re-filter vs final max, exp + PV (two row passes) ----
#pragma unroll
  for (int rs = 0; rs < 2; ++rs) {
    const int row = rs * 64 + (tid >> 2), seg = tid & 3;
    const unsigned n = cnt[row];
    const int gs = s0 + row;
    if (n > ACAP) {
      if (seg == 0) {
        const unsigned i = atomicAdd(ovcount, 1u);
        ovlist[i] = (unsigned)(bh * 2048 + gs);
      }
    } else {
      const float mf = mrow[row];
      float o[16];
#pragma unroll
      for (int u = 0; u < 16; ++u) o[u] = 0.f;
      float l = 0.f;
      for (unsigned i = 0; i < n; ++i) {
        const float d = LL[row * ACAP + i] - mf;
        if (d > -80.f) {
          const int c = cL[row * ACAP + i];
          const float p = expf(d);
          l += p;
          const uint4* vp = (const uint4*)(vh + (size_t)c * 64 + seg * 16);
          const uint4 t0 = vp[0], t1 = vp[1];
          const uint wds[8] = {t0.x,t0.y,t0.z,t0.w,t1.x,t1.y,t1.z,t1.w};
#pragma unroll
          for (int u = 0; u < 8; ++u) {
            o[u*2]   += p * b2f((ushort)(wds[u] & 0xffff));
            o[u*2+1] += p * b2f((ushort)(wds[u] >> 16));
          }
        }
      }
      const float inv = 1.f / l;
      ushort* op = ctx + (((size_t)b * 2048) + gs) * 1024 + h * 64 + seg * 16;
      uint pk[8];
#pragma unroll
      for (int u = 0; u < 8; ++u)
        pk[u] = (uint)f2h_u(o[2*u] * inv) | ((uint)f2h_u(o[2*u+1] * inv) << 16);
      *(uint4*)(op)     = make_uint4(pk[0], pk[1], pk[2], pk[3]);
      *(uint4*)(op + 8) = make_uint4(pk[4], pk[5], pk[6], pk[7]);
    }
  }
}

// ---------------------------------------------------------------------------
// Key-parallel dense cleanup (unchanged): one block per flagged row.
// ---------------------------------------------------------------------------
__global__ __launch_bounds__(256) void attn_cleanup2_k(
    const float* __restrict__ qb, const float* __restrict__ kb,
    const ushort* __restrict__ vb, ushort* __restrict__ ctx,
    const unsigned* __restrict__ ovcount, const unsigned* __restrict__ ovlist)
{
  __shared__ float Ls[2048];
  __shared__ float osum[32][65];
  __shared__ float wm[4], wl[4];
  const unsigned count = *ovcount;
  const int tid = threadIdx.x;
  const int seg = tid & 7;
  const int kq  = tid >> 3;
  const int wave = tid >> 6;

  for (unsigned idx = blockIdx.x; idx < count; idx += gridDim.x) {
    const unsigned r = ovlist[idx];
    const int gs = (int)(r & 2047u);
    const size_t bh = (size_t)(r >> 11);
    const int b = (int)(bh >> 4), h = (int)(bh & 15);
    const float*  qh = qb + bh * (2048 * 64);
    const float*  kh = kb + bh * (2048 * 64);
    const ushort* vh = vb + bh * (2048 * 64);

    float q[8];
    {
      const float4* qp = (const float4*)(qh + (size_t)gs * 64 + seg * 8);
      const float4 t0 = qp[0], t1 = qp[1];
      q[0]=t0.x; q[1]=t0.y; q[2]=t0.z; q[3]=t0.w;
      q[4]=t1.x; q[5]=t1.y; q[6]=t1.z; q[7]=t1.w;
    }
    const float sq = (float)gs;

    float mloc = -3.0e38f;
    for (int it = 0; it < 64; ++it) {
      const int c = it * 32 + kq;
      const float4* kp = (const float4*)(kh + (size_t)c * 64 + seg * 8);
      const float4 a = kp[0], bb = kp[1];
      float dt = q[0]*a.x + q[1]*a.y + q[2]*a.z + q[3]*a.w
               + q[4]*bb.x + q[5]*bb.y + q[6]*bb.z + q[7]*bb.w;
      dt += __shfl_xor(dt, 1);
      dt += __shfl_xor(dt, 2);
      dt += __shfl_xor(dt, 4);
      const float L = dt * sq * (float)c;
      if (seg == 0) Ls[c] = L;
      mloc = fmaxf(mloc, L);
    }
    mloc = fmaxf(mloc, __shfl_xor(mloc, 8));
    mloc = fmaxf(mloc, __shfl_xor(mloc, 16));
    mloc = fmaxf(mloc, __shfl_xor(mloc, 32));
    if ((tid & 63) == 0) wm[wave] = mloc;
    __syncthreads();
    const float m = fmaxf(fmaxf(wm[0], wm[1]), fmaxf(wm[2], wm[3]));

    float o[8] = {0.f,0.f,0.f,0.f,0.f,0.f,0.f,0.f};
    float lloc = 0.f;
    for (int it = 0; it < 64; ++it) {
      const int c = it * 32 + kq;
      const float p = expf(Ls[c] - m);
      lloc += p;
      const uint4 vv = *(const uint4*)(vh + (size_t)c * 64 + seg * 8);
      o[0] += p * b2f((ushort)(vv.x & 0xffff)); o[1] += p * b2f((ushort)(vv.x >> 16));
      o[2] += p * b2f((ushort)(vv.y & 0xffff)); o[3] += p * b2f((ushort)(vv.y >> 16));
      o[4] += p * b2f((ushort)(vv.z & 0xffff)); o[5] += p * b2f((ushort)(vv.z >> 16));
      o[6] += p * b2f((ushort)(vv.w & 0xffff)); o[7] += p * b2f((ushort)(vv.w >> 16));
    }
    lloc += __shfl_xor(lloc, 8);
    lloc += __shfl_xor(lloc, 16);
    lloc += __shfl_xor(lloc, 32);
    if ((tid & 63) == 0) wl[wave] = lloc;
#pragma unroll
    for (int u = 0; u < 8; ++u) osum[kq][seg * 8 + u] = o[u];
    __syncthreads();
    const float l = (wl[0] + wl[1]) + (wl[2] + wl[3]);
    if (tid < 64) {
      float acc = 0.f;
#pragma unroll
      for (int k2 = 0; k2 < 32; ++k2) acc += osum[k2][tid];
      ctx[(((size_t)b * 2048) + gs) * 1024 + h * 64 + tid] = f2h_u(acc / l);
    }
    __syncthreads();
  }
}

// ---------------------------------------------------------------------------
// Fallback attention (38 MB path), unchanged.
// ---------------------------------------------------------------------------
template<int RPT, int OF16>
__global__ __launch_bounds__(256) void attn_k(
    const float* __restrict__ qb, const float* __restrict__ kb,
    const ushort* __restrict__ vb, ushort* __restrict__ ctx,
    int b0, size_t bstrF, size_t bstrU)
{
  __shared__ float kS[64][64];
  __shared__ float vS[64][64];
  const int tid = threadIdx.x;
  const int h  = blockIdx.y;
  const int bz = blockIdx.z;
  const int b  = b0 + bz;
  const float*  qh = qb + bstrF * bz + (size_t)h * 2048 * 64;
  const float*  kh = kb + bstrF * bz + (size_t)h * 2048 * 64;
  const ushort* vh = vb + bstrU * bz + (size_t)h * 2048 * 64;

  const int seg  = tid & 3;
  const int slot = tid >> 2;
  const int row0 = blockIdx.x * (64 * RPT) + slot * RPT;

  f32x2 qv[RPT][8], o[RPT][8];
  float m[RPT], l[RPT], sq[RPT];
#pragma unroll
  for (int i = 0; i < RPT; ++i) {
    const float4* qp = (const float4*)(qh + (size_t)(row0 + i) * 64 + seg * 16);
#pragma unroll
    for (int w = 0; w < 4; ++w) {
      const float4 t = qp[w];
      qv[i][2*w]   = f32x2{t.x, t.y};
      qv[i][2*w+1] = f32x2{t.z, t.w};
    }
    m[i] = -3.0e38f; l[i] = 0.f; sq[i] = (float)(row0 + i);
#pragma unroll
    for (int t = 0; t < 8; ++t) o[i][t] = f32x2{0.f, 0.f};
  }

  for (int c0 = 0; c0 < 2048; c0 += 64) {
    __syncthreads();
    {
      const int key = tid >> 2, sg = tid & 3;
      const float4* sp = (const float4*)(kh + (size_t)(c0 + key) * 64 + sg * 16);
      float4* dp = (float4*)&kS[key][sg * 16];
#pragma unroll
      for (int u = 0; u < 4; ++u) dp[u] = sp[u];
      const uint4* vp = (const uint4*)(vh + (size_t)(c0 + key) * 64 + sg * 16);
      float* vd = &vS[key][sg * 16];
#pragma unroll
      for (int u = 0; u < 2; ++u) {
        const uint4 t = vp[u];
        vd[u*8+0] = b2f((ushort)(t.x & 0xffff)); vd[u*8+1] = b2f((ushort)(t.x >> 16));
        vd[u*8+2] = b2f((ushort)(t.y & 0xffff)); vd[u*8+3] = b2f((ushort)(t.y >> 16));
        vd[u*8+4] = b2f((ushort)(t.z & 0xffff)); vd[u*8+5] = b2f((ushort)(t.z >> 16));
        vd[u*8+6] = b2f((ushort)(t.w & 0xffff)); vd[u*8+7] = b2f((ushort)(t.w >> 16));
      }
    }
    __syncthreads();
#pragma unroll 2
    for (int j = 0; j < 64; ++j) {
      const float4* kp = (const float4*)&kS[j][seg * 16];
      const float4 ka = kp[0], kb4 = kp[1], kc = kp[2], kd = kp[3];
      const f32x2 K0 = {ka.x, ka.y},  K1 = {ka.z, ka.w};
      const f32x2 K2 = {kb4.x, kb4.y}, K3 = {kb4.z, kb4.w};
      const f32x2 K4 = {kc.x, kc.y},  K5 = {kc.z, kc.w};
      const f32x2 K6 = {kd.x, kd.y},  K7 = {kd.z, kd.w};
      float dt[RPT];
#pragma unroll
      for (int i = 0; i < RPT; ++i) {
        f32x2 a2 = qv[i][0] * K0;
        a2 += qv[i][1] * K1;
        a2 += qv[i][2] * K2;
        a2 += qv[i][3] * K3;
        a2 += qv[i][4] * K4;
        a2 += qv[i][5] * K5;
        a2 += qv[i][6] * K6;
        a2 += qv[i][7] * K7;
        dt[i] = a2[0] + a2[1];
      }
#pragma unroll
      for (int i = 0; i < RPT; ++i) {
        dt[i] += __shfl_xor(dt[i], 1);
        dt[i] += __shfl_xor(dt[i], 2);
      }
      const float cc = (float)(c0 + j);
#pragma unroll
      for (int i = 0; i < RPT; ++i) {
        const float L = dt[i] * sq[i] * cc;
        const float d = L - m[i];
        if (d > 0.f) {
          const float r = expf(-d);
          l[i] = l[i] * r + 1.f;
          m[i] = L;
          const f32x2 r2 = {r, r};
          const float4* vp4 = (const float4*)&vS[j][seg * 16];
          const float4 va = vp4[0], vb4 = vp4[1], vc = vp4[2], vd4 = vp4[3];
          const f32x2 V[8] = {{va.x,va.y},{va.z,va.w},{vb4.x,vb4.y},{vb4.z,vb4.w},
                              {vc.x,vc.y},{vc.z,vc.w},{vd4.x,vd4.y},{vd4.z,vd4.w}};
#pragma unroll
          for (int t = 0; t < 8; ++t) o[i][t] = o[i][t] * r2 + V[t];
        } else if (d > -80.f) {
          const float p = expf(d);
          l[i] += p;
          const f32x2 p2 = {p, p};
          const float4* vp4 = (const float4*)&vS[j][seg * 16];
          const float4 va = vp4[0], vb4 = vp4[1], vc = vp4[2], vd4 = vp4[3];
          const f32x2 V[8] = {{va.x,va.y},{va.z,va.w},{vb4.x,vb4.y},{vb4.z,vb4.w},
                              {vc.x,vc.y},{vc.z,vc.w},{vd4.x,vd4.y},{vd4.z,vd4.w}};
#pragma unroll
          for (int t = 0; t < 8; ++t) o[i][t] += p2 * V[t];
        }
      }
    }
  }

#pragma unroll
  for (int i = 0; i < RPT; ++i) {
    const float inv = 1.f / l[i];
    ushort* op = ctx + (((size_t)b * 2048) + row0 + i) * 1024 + h * 64 + seg * 16;
    uint pk[8];
#pragma unroll
    for (int t2 = 0; t2 < 8; ++t2) {
      const uint lo = OF16 ? (uint)f2h_u(o[i][t2][0] * inv) : (uint)f2b(o[i][t2][0] * inv);
      const uint hi = OF16 ? (uint)f2h_u(o[i][t2][1] * inv) : (uint)f2b(o[i][t2][1] * inv);
      pk[t2] = lo | (hi << 16);
    }
    *(uint4*)(op)     = make_uint4(pk[0], pk[1], pk[2], pk[3]);
    *(uint4*)(op + 8) = make_uint4(pk[4], pk[5], pk[6], pk[7]);
  }
}

// ---------------------------------------------------------------------------
// LayerNorm 1024 cols, bf16 in -> bf16 out (fallback path).
// ---------------------------------------------------------------------------
__global__ __launch_bounds__(256) void ln_k(const ushort* __restrict__ y,
                                            const void* __restrict__ g,
                                            const void* __restrict__ be,
                                            const int* __restrict__ fp,
                                            ushort* __restrict__ out)
{
  const int row = blockIdx.x, tid = threadIdx.x;
  const int f = *fp;
  const ushort* p = y + (size_t)row * 1024;
  float v[4], s = 0.f, s2 = 0.f;
#pragma unroll
  for (int i = 0; i < 4; ++i) {
    const float x = b2f(p[tid + i * 256]);
    v[i] = x; s += x; s2 += x * x;
  }
#pragma unroll
  for (int off = 1; off < 64; off <<= 1) { s += __shfl_xor(s, off); s2 += __shfl_xor(s2, off); }
  __shared__ float red[8];
  const int wave = tid >> 6, lane = tid & 63;
  if (lane == 0) { red[wave] = s; red[4 + wave] = s2; }
  __syncthreads();
  s = red[0] + red[1] + red[2] + red[3];
  s2 = red[4] + red[5] + red[6] + red[7];
  const float mu = s * (1.f / 1024.f);
  const float var = s2 * (1.f / 1024.f) - mu * mu;
  const float rstd = rsqrtf(var + 1e-5f);
  ushort* o = out + (size_t)row * 1024;
#pragma unroll
  for (int i = 0; i < 4; ++i) {
    const int c = tid + i * 256;
    o[c] = f2b((v[i] - mu) * rstd * ldf(g, c, f) + ldf(be, c, f));
  }
}

// ---------------------------------------------------------------------------
// LayerNorm 1024 cols, f16 in -> f16 out (main path).
// ---------------------------------------------------------------------------
__global__ __launch_bounds__(256) void ln_h_k(const _Float16* __restrict__ y,
                                              const void* __restrict__ g,
                                              const void* __restrict__ be,
                                              const int* __restrict__ fp,
                                              _Float16* __restrict__ out)
{
  const int row = blockIdx.x, tid = threadIdx.x;
  const int f = *fp;
  const _Float16* p = y + (size_t)row * 1024;
  float v[4], s = 0.f, s2 = 0.f;
#pragma unroll
  for (int i = 0; i < 4; ++i) {
    const float x = (float)p[tid + i * 256];
    v[i] = x; s += x; s2 += x * x;
  }
#pragma unroll
  for (int off = 1; off < 64; off <<= 1) { s += __shfl_xor(s, off); s2 += __shfl_xor(s2, off); }
  __shared__ float red[8];
  const int wave = tid >> 6, lane = tid & 63;
  if (lane == 0) { red[wave] = s; red[4 + wave] = s2; }
  __syncthreads();
  s = red[0] + red[1] + red[2] + red[3];
  s2 = red[4] + red[5] + red[6] + red[7];
  const float mu = s * (1.f / 1024.f);
  const float var = s2 * (1.f / 1024.f) - mu * mu;
  const float rstd = rsqrtf(var + 1e-5f);
  _Float16* o = out + (size_t)row * 1024;
#pragma unroll
  for (int i = 0; i < 4; ++i) {
    const int c = tid + i * 256;
    o[c] = (_Float16)((v[i] - mu) * rstd * ldf(g, c, f) + ldf(be, c, f));
  }
}

// ---------------------------------------------------------------------------
// Final LayerNorm: fp32 in/out, in place on d_out.
// ---------------------------------------------------------------------------
__global__ __launch_bounds__(256) void ln_f32_k(float* __restrict__ y,
                                                const void* __restrict__ g,
                                                const void* __restrict__ be,
                                                const int* __restrict__ fp)
{
  const int row = blockIdx.x, tid = threadIdx.x;
  const int f = *fp;
  float* p = y + (size_t)row * 1024;
  float v[4], s = 0.f, s2 = 0.f;
#pragma unroll
  for (int i = 0; i < 4; ++i) {
    const float x = p[tid + i * 256];
    v[i] = x; s += x; s2 += x * x;
  }
#pragma unroll
  for (int off = 1; off < 64; off <<= 1) { s += __shfl_xor(s, off); s2 += __shfl_xor(s2, off); }
  __shared__ float red[8];
  const int wave = tid >> 6, lane = tid & 63;
  if (lane == 0) { red[wave] = s; red[4 + wave] = s2; }
  __syncthreads();
  s = red[0] + red[1] + red[2] + red[3];
  s2 = red[4] + red[5] + red[6] + red[7];
  const float mu = s * (1.f / 1024.f);
  const float var = s2 * (1.f / 1024.f) - mu * mu;
  const float rstd = rsqrtf(var + 1e-5f);
#pragma unroll
  for (int i = 0; i < 4; ++i) {
    const int c = tid + i * 256;
    p[c] = (v[i] - mu) * rstd * ldf(g, c, f) + ldf(be, c, f);
  }
}

// ---------------------------------------------------------------------------
extern "C" void kernel_launch(void* const* d_in, const int* in_sizes, int n_in,
                              void* d_out, int out_size, void* d_ws, size_t ws_size,
                              hipStream_t stream)
{
  const void* x  = d_in[0];
  const void* wq = d_in[1];  const void* bq = d_in[2];
  const void* wk = d_in[3];  const void* bk = d_in[4];
  const void* wv = d_in[5];  const void* bv = d_in[6];
  const void* wo = d_in[7];  const void* bo = d_in[8];
  const void* w1 = d_in[9];  const void* b1 = d_in[10];
  const void* w2 = d_in[11]; const void* b2 = d_in[12];
  const void* g1 = d_in[13]; const void* be1 = d_in[14];
  const void* g2 = d_in[15]; const void* be2 = d_in[16];
  float* outp = (float*)d_out;

  const size_t MB = 1048576;
  char* ws = (char*)d_ws;
  int*      flag    = (int*)(ws + 0);
  int*      zeroc   = (int*)(ws + 64);
  unsigned* ovcount = (unsigned*)(ws + 128);
  float*    wtab    = (float*)(ws + 256);

  detect_k<<<dim3(1), dim3(64), 0, stream>>>(x, flag);
  wtab_k<<<dim3(1), dim3(64), 0, stream>>>(wtab, zeroc, ovcount);

  const size_t QS = (size_t)16 * 2048 * 64;   // per-batch q/k/v element count

  if (ws_size >= (size_t)98 * MB) {
    // ---- main path (97.5 MB peak) ----
    float*     qb   = (float*)(ws + 1 * MB);
    float*     kb   = (float*)(ws + 33 * MB);
    ushort*    vb   = (ushort*)(ws + 65 * MB);
    ushort*    ctxh = (ushort*)(ws + 81 * MB);      // f16 bits
    unsigned*  ovlist = (unsigned*)(ws + 97 * MB);  // [131072] u32
    _Float16*  WoT  = (_Float16*)(ws + 65 * MB);
    _Float16*  W1T  = (_Float16*)(ws + 67 * MB);
    _Float16*  W2T  = (_Float16*)(ws + 75 * MB);
    _Float16*  y1h  = (_Float16*)(ws + 1 * MB);
    _Float16*  hh   = (_Float16*)(ws + 17 * MB);
    _Float16*  ffc  = (_Float16*)(ws + 33 * MB);

    // QKV: one fused dispatch per projection, M = 8192
    sgemm2<0><<<dim3(8, 64), 256, 0, stream>>>(x, flag, wq, bq, flag,
                                               nullptr, qb, wtab, 1024, 1024);
    sgemm2<1><<<dim3(8, 64), 256, 0, stream>>>(x, flag, wk, bk, flag,
                                               nullptr, kb, wtab, 1024, 1024);
    sgemm2<2><<<dim3(8, 64), 256, 0, stream>>>(x, flag, wv, bv, flag,
                                               vb, nullptr, wtab, 1024, 1024);

    // single-pass MFMA attention (128 rows/block) + key-parallel cleanup
    attn_mfma_k<<<dim3(16, 16, 4), 256, 0, stream>>>(qb, kb, vb, ctxh,
                                                     ovcount, ovlist);
    attn_cleanup2_k<<<dim3(8192), 256, 0, stream>>>(qb, kb, vb, ctxh,
                                                    ovcount, ovlist);

    cvt_wT_k<<<dim3(32, 32),  256, 0, stream>>>(wo, flag, WoT, 1024, 1024);
    cvt_wT_k<<<dim3(128, 32), 256, 0, stream>>>(w1, flag, W1T, 1024, 4096);

    hgemm<4, 128><<<dim3(8, 64), 256, 0, stream>>>((const _Float16*)ctxh, 0, WoT,
                                                   bo, flag, x, flag, nullptr,
                                                   y1h, nullptr, 1024, 1024, 0);
    cvt_wT_k<<<dim3(32, 128), 256, 0, stream>>>(w2, flag, W2T, 4096, 1024);

    ln_h_k<<<dim3(8192), 256, 0, stream>>>(y1h, g1, be1, flag, hh);

    for (int c = 0; c < 2; ++c) {
      hgemm<3, 128><<<dim3(32, 32), 256, 0, stream>>>(hh, c * 4096, W1T,
                                                      b1, flag, nullptr, zeroc, nullptr,
                                                      ffc, nullptr, 4096, 1024, 0);
      hgemm<5, 64><<<dim3(8, 64), 256, 0, stream>>>(ffc, 0, W2T,
                                                    b2, flag, nullptr, zeroc, hh,
                                                    nullptr, outp, 1024, 4096, c * 4096);
    }
    ln_f32_k<<<dim3(8192), 256, 0, stream>>>(outp, g2, be2, flag);
  } else {
    // ---- fallback: original 38 MB layout, bf16 everywhere ----
    float*  qb   = (float*)(ws + 1 * MB);
    float*  kb   = (float*)(ws + 9 * MB);
    ushort* vb   = (ushort*)(ws + 17 * MB);
    ushort* ctxb = (ushort*)(ws + 22 * MB);
    ushort* y1   = (ushort*)(ws + 1 * MB);
    ushort* hbuf = (ushort*)(ws + 22 * MB);
    ushort* ffc  = (ushort*)(ws + 1 * MB);

    for (int b = 0; b < 4; ++b) {
      sgemm<0><<<dim3(16, 32), 256, 0, stream>>>(x, flag, b * 2048, wq, bq, flag,
                                                 nullptr, nullptr, nullptr, qb, wtab,
                                                 1024, 1024, b * 2048);
      sgemm<1><<<dim3(16, 32), 256, 0, stream>>>(x, flag, b * 2048, wk, bk, flag,
                                                 nullptr, nullptr, nullptr, kb, wtab,
                                                 1024, 1024, b * 2048);
      sgemm<2><<<dim3(16, 32), 256, 0, stream>>>(x, flag, b * 2048, wv, bv, flag,
                                                 nullptr, nullptr, vb, nullptr, wtab,
                                                 1024, 1024, b * 2048);
      attn_k<1, 0><<<dim3(32, 16, 1), 256, 0, stream>>>(qb, kb, vb, ctxb, b, 0, 0);
    }

    sgemm<4><<<dim3(16, 128), 256, 0, stream>>>(ctxb, zeroc, 0, wo, bo, flag,
                                                x, flag, y1, nullptr, wtab,
                                                1024, 1024, 0);
    ln_k<<<dim3(8192), 256, 0, stream>>>(y1, g1, be1, flag, hbuf);
    for (int c = 0; c < 4; ++c) {
      sgemm<3><<<dim3(64, 32), 256, 0, stream>>>(hbuf, zeroc, c * 2048, w1, b1, flag,
                                                 nullptr, nullptr, ffc, nullptr, wtab,
                                                 4096, 1024, 0);
      sgemm<5><<<dim3(16, 32), 256, 0, stream>>>(ffc, zeroc, 0, w2, b2, flag,
                                                 hbuf, zeroc, nullptr, outp, wtab,
                                                 1024, 4096, c * 2048);
    }
    ln_f32_k<<<dim3(8192), 256, 0, stream>>>(outp, g2, be2, flag);
  }
}

// Round 8
// 1558.344 us; speedup vs baseline: 1.0047x; 1.0047x over previous
//
#include <hip/hip_runtime.h>

typedef _Float16 f16x8 __attribute__((ext_vector_type(8)));
typedef float    f32x4 __attribute__((ext_vector_type(4)));
typedef float    f32x2 __attribute__((ext_vector_type(2)));
typedef short    bf16x8 __attribute__((ext_vector_type(8)));

__device__ __forceinline__ float b2f(ushort u){
  union { float f; unsigned int i; } v; v.i = ((unsigned int)u) << 16; return v.f;
}
__device__ __forceinline__ ushort f2b(float f){
  union { float f; unsigned int i; } v; v.f = f;
  unsigned int r = (v.i + 0x7FFFu + ((v.i >> 16) & 1u)) >> 16;
  return (ushort)r;
}
__device__ __forceinline__ ushort f2h_u(float f){
  union { _Float16 h; ushort u; } v; v.h = (_Float16)f; return v.u;
}
// flag-typed load: f=1 -> fp32 array, f=0 -> bf16(ushort) array
__device__ __forceinline__ float ldf(const void* p, size_t i, int f){
  return f ? ((const float*)p)[i] : b2f(((const ushort*)p)[i]);
}

// ---------------------------------------------------------------------------
// Input storage detector on x: packed bf16 -> 0 ; fp32 (any) -> 1.
// ---------------------------------------------------------------------------
__global__ void detect_k(const void* __restrict__ x, int* __restrict__ flag)
{
  const int lane = threadIdx.x; // 64
  const ushort* p = (const ushort*)x;
  int wild = 0, zeven = 0;
#pragma unroll
  for (int j = 0; j < 8; ++j) {
    const int idx = lane * 8 + j;
    const ushort u = p[idx];
    if (((u >> 7) & 0xFF) >= 0xF1) ++wild;
    if (((idx & 1) == 0) && u == 0) ++zeven;
  }
#pragma unroll
  for (int off = 1; off < 64; off <<= 1) {
    wild += __shfl_xor(wild, off);
    zeven += __shfl_xor(zeven, off);
  }
  if (lane == 0) *flag = (wild >= 4 || zeven >= 128) ? 1 : 0;
}

// W table: logits = sq*sk * sum_d wt[d]*q_d*k_d  with 1/8 folded in.
// Also zeroes the overflow-row counter each launch.
__global__ void wtab_k(float* __restrict__ w, int* __restrict__ zeroc,
                       unsigned* __restrict__ ovc)
{
  const int d = threadIdx.x; // 64
  const int i = (d >> 1) & 15;
  const double F2 = pow(10000.0, -(double)i / 8.0);
  const double G2 = pow(10000.0, -(double)(2 * i + 1) / 16.0);
  w[d] = (float)((F2 + G2) * 0.125);
  if (d == 0) { *zeroc = 0; *ovc = 0u; }
}

// ---------------------------------------------------------------------------
// Weight convert + transpose: W[K][N] (flag-typed) -> Wt[N][K] f16.
// ---------------------------------------------------------------------------
__global__ __launch_bounds__(256) void cvt_wT_k(const void* __restrict__ W,
    const int* __restrict__ fp, _Float16* __restrict__ Wt, int K, int N)
{
  __shared__ float t[32][33];
  const int f = *fp;
  const int n0 = blockIdx.x * 32, k0 = blockIdx.y * 32;
  const int ln = threadIdx.x & 31, lr = threadIdx.x >> 5;
#pragma unroll
  for (int u = 0; u < 4; ++u) {
    const int kk = lr + u * 8;
    t[kk][ln] = ldf(W, (size_t)(k0 + kk) * N + n0 + ln, f);
  }
  __syncthreads();
#pragma unroll
  for (int u = 0; u < 4; ++u) {
    const int nn = lr + u * 8;
    Wt[(size_t)(n0 + nn) * K + k0 + ln] = (_Float16)t[ln][nn];
  }
}

// ---------------------------------------------------------------------------
// fp32 VALU GEMM, 128x128 tile, 8x8 per thread. QKV scatter modes only.
// (unchanged -- bit-identical q/k/v)
// ---------------------------------------------------------------------------
template<int MODE>
__global__ __launch_bounds__(256) void sgemm2(
    const void* __restrict__ A, const int* __restrict__ afp,
    const void* __restrict__ W, const void* __restrict__ bias,
    const int* __restrict__ wfp,
    ushort* __restrict__ outU, float* __restrict__ outF,
    const float* __restrict__ wtab,
    int N, int K)
{
  __shared__ float As[16][128];   // [kk][row] (transposed on store)
  __shared__ float Ws[16][132];   // [kk][col] padded
  const int tid = threadIdx.x;
  const int tx = tid & 15, ty = tid >> 4;
  const int bn = blockIdx.x * 128, bm = blockIdx.y * 128;
  const int af = *afp, wf = *wfp;

  float acc[8][8] = {};

  for (int k0 = 0; k0 < K; k0 += 16) {
    __syncthreads();
    {   // stage A: 128 rows x 16 k, transposed into As[kk][row]
      const int row = tid >> 1, kk0 = (tid & 1) * 8;
      float tmp[8];
      if (af) {
        const float4* p = (const float4*)((const float*)A + (size_t)(bm + row) * K + k0 + kk0);
        const float4 a = p[0], b = p[1];
        tmp[0]=a.x; tmp[1]=a.y; tmp[2]=a.z; tmp[3]=a.w;
        tmp[4]=b.x; tmp[5]=b.y; tmp[6]=b.z; tmp[7]=b.w;
      } else {
        const uint4 u = *(const uint4*)((const ushort*)A + (size_t)(bm + row) * K + k0 + kk0);
        tmp[0]=b2f((ushort)(u.x&0xffff)); tmp[1]=b2f((ushort)(u.x>>16));
        tmp[2]=b2f((ushort)(u.y&0xffff)); tmp[3]=b2f((ushort)(u.y>>16));
        tmp[4]=b2f((ushort)(u.z&0xffff)); tmp[5]=b2f((ushort)(u.z>>16));
        tmp[6]=b2f((ushort)(u.w&0xffff)); tmp[7]=b2f((ushort)(u.w>>16));
      }
#pragma unroll
      for (int u = 0; u < 8; ++u) As[kk0 + u][row] = tmp[u];
    }
    {   // stage W: 16 k x 128 cols
      const int kk = tid >> 4, c0 = (tid & 15) * 8;
      float tmp[8];
      if (wf) {
        const float4* p = (const float4*)((const float*)W + (size_t)(k0 + kk) * N + bn + c0);
        const float4 a = p[0], b = p[1];
        tmp[0]=a.x; tmp[1]=a.y; tmp[2]=a.z; tmp[3]=a.w;
        tmp[4]=b.x; tmp[5]=b.y; tmp[6]=b.z; tmp[7]=b.w;
      } else {
        const uint4 u = *(const uint4*)((const ushort*)W + (size_t)(k0 + kk) * N + bn + c0);
        tmp[0]=b2f((ushort)(u.x&0xffff)); tmp[1]=b2f((ushort)(u.x>>16));
        tmp[2]=b2f((ushort)(u.y&0xffff)); tmp[3]=b2f((ushort)(u.y>>16));
        tmp[4]=b2f((ushort)(u.z&0xffff)); tmp[5]=b2f((ushort)(u.z>>16));
        tmp[6]=b2f((ushort)(u.w&0xffff)); tmp[7]=b2f((ushort)(u.w>>16));
      }
      *(float4*)&Ws[kk][c0]     = make_float4(tmp[0], tmp[1], tmp[2], tmp[3]);
      *(float4*)&Ws[kk][c0 + 4] = make_float4(tmp[4], tmp[5], tmp[6], tmp[7]);
    }
    __syncthreads();
#pragma unroll
    for (int kk = 0; kk < 16; ++kk) {
      float ar[8], wr[8];
      const float4 a0 = *(const float4*)&As[kk][ty * 8];
      const float4 a1 = *(const float4*)&As[kk][ty * 8 + 4];
      ar[0]=a0.x; ar[1]=a0.y; ar[2]=a0.z; ar[3]=a0.w;
      ar[4]=a1.x; ar[5]=a1.y; ar[6]=a1.z; ar[7]=a1.w;
      const float4 w0 = *(const float4*)&Ws[kk][tx * 8];
      const float4 w1 = *(const float4*)&Ws[kk][tx * 8 + 4];
      wr[0]=w0.x; wr[1]=w0.y; wr[2]=w0.z; wr[3]=w0.w;
      wr[4]=w1.x; wr[5]=w1.y; wr[6]=w1.z; wr[7]=w1.w;
#pragma unroll
      for (int i = 0; i < 8; ++i)
#pragma unroll
        for (int j = 0; j < 8; ++j) acc[i][j] += ar[i] * wr[j];
    }
  }

#pragma unroll
  for (int i = 0; i < 8; ++i) {
    const int gr = bm + ty * 8 + i;
    const int b = gr >> 11, s = gr & 2047;
#pragma unroll
    for (int j = 0; j < 8; ++j) {
      const int gc = bn + tx * 8 + j;
      float v = acc[i][j] + ldf(bias, gc, wf);
      const int hh = gc >> 6, dh = gc & 63;
      const size_t idx = (size_t)b * 2097152 + (((size_t)hh * 2048) + s) * 64 + dh;
      if (MODE == 0)      outF[idx] = v * wtab[dh];
      else if (MODE == 1) outF[idx] = v;
      else                outU[idx] = f2b(v);
    }
  }
}

// ---------------------------------------------------------------------------
// fp32 VALU GEMM (fallback path, unchanged).
// ---------------------------------------------------------------------------
template<int MODE>
__global__ __launch_bounds__(256) void sgemm(
    const void* __restrict__ A, const int* __restrict__ afp, int arow0,
    const void* __restrict__ W, const void* __restrict__ bias,
    const int* __restrict__ wfp,
    const void* __restrict__ res, const int* __restrict__ rfp,
    ushort* __restrict__ outU, float* __restrict__ outF,
    const float* __restrict__ wtab,
    int N, int K, int erow0)
{
  __shared__ float As[64][17];
  __shared__ float Ws[16][65];
  const int tid = threadIdx.x;
  const int tx = tid & 15, ty = tid >> 4;
  const int bn = blockIdx.x * 64, bm = blockIdx.y * 64;
  const int af = *afp, wf = *wfp;

  float acc[4][4] = {};

  for (int k0 = 0; k0 < K; k0 += 16) {
    __syncthreads();
#pragma unroll
    for (int u = 0; u < 4; ++u) {
      const int idx = tid * 4 + u;
      const int row = idx >> 4, kk = idx & 15;
      As[row][kk] = ldf(A, (size_t)(arow0 + bm + row) * K + k0 + kk, af);
    }
#pragma unroll
    for (int u = 0; u < 4; ++u) {
      const int idx = tid * 4 + u;
      const int kk = idx >> 6, col = idx & 63;
      Ws[kk][col] = ldf(W, (size_t)(k0 + kk) * N + bn + col, wf);
    }
    __syncthreads();
#pragma unroll
    for (int kk = 0; kk < 16; ++kk) {
      float ar[4], wr[4];
#pragma unroll
      for (int i = 0; i < 4; ++i) ar[i] = As[ty * 4 + i][kk];
#pragma unroll
      for (int j = 0; j < 4; ++j) wr[j] = Ws[kk][tx * 4 + j];
#pragma unroll
      for (int i = 0; i < 4; ++i)
#pragma unroll
        for (int j = 0; j < 4; ++j) acc[i][j] += ar[i] * wr[j];
    }
  }

  const int rf = (MODE >= 4) ? *rfp : 0;
#pragma unroll
  for (int i = 0; i < 4; ++i) {
    const int gr = erow0 + bm + ty * 4 + i;
#pragma unroll
    for (int j = 0; j < 4; ++j) {
      const int gc = bn + tx * 4 + j;
      float v = acc[i][j] + ldf(bias, gc, wf);
      if (MODE == 0) {
        const int hh = gc >> 6, dh = gc & 63, s = gr & 2047;
        outF[(((size_t)hh * 2048) + s) * 64 + dh] = v * wtab[dh];
      } else if (MODE == 1) {
        const int hh = gc >> 6, dh = gc & 63, s = gr & 2047;
        outF[(((size_t)hh * 2048) + s) * 64 + dh] = v;
      } else if (MODE == 2) {
        const int hh = gc >> 6, dh = gc & 63, s = gr & 2047;
        outU[(((size_t)hh * 2048) + s) * 64 + dh] = f2b(v);
      } else if (MODE == 3) {
        outU[(size_t)gr * N + gc] = f2b(fmaxf(v, 0.f));
      } else if (MODE == 4) {
        v += ldf(res, (size_t)gr * 1024 + gc, rf);
        outU[(size_t)gr * 1024 + gc] = f2b(v);
      } else {
        v += ldf(res, (size_t)gr * 1024 + gc, rf);
        outF[(size_t)gr * 1024 + gc] = v;
      }
    }
  }
}

// ---------------------------------------------------------------------------
// f16 MFMA GEMM v3: LDS rows padded 64B -> 80B ([.][40] f16) so the MFMA
// fragment ds_read_b128 pattern (16 lanes, consecutive rows, fixed 16B col)
// maps to bank-group (20*row + 4g) mod 32 -> 2-way (free) instead of the
// previous 8-way conflict. global_load_lds can't write padded layouts, so
// staging is reg-staged ds_write_b128 (proven neutral r5->r6). Bytes moved
// and MFMA order identical -> bit-identical results.
// ---------------------------------------------------------------------------
template<int MODE, int TM>
__global__ __launch_bounds__(256) void hgemm(
    const _Float16* __restrict__ A, int arow0,
    const _Float16* __restrict__ Wt,
    const void* __restrict__ bias, const int* __restrict__ bfp,
    const void* __restrict__ res, const int* __restrict__ rfp,
    const _Float16* __restrict__ resH,
    _Float16* __restrict__ outH, float* __restrict__ outF,
    int N, int K, int erow0)
{
  constexpr int MF = TM / 32;
  __shared__ _Float16 As[TM][40];    // 80B padded rows
  __shared__ _Float16 Bs[128][40];
  const int tid = threadIdx.x;
  const int lane = tid & 63;
  const int w = tid >> 6;
  const int wm = w >> 1, wn = w & 1;
  const int fr = lane & 15, g = lane >> 4;
  const int bn = blockIdx.x * 128, bm = blockIdx.y * TM;

  f32x4 acc[MF][4];
#pragma unroll
  for (int m = 0; m < MF; ++m)
#pragma unroll
    for (int n = 0; n < 4; ++n)
      acc[m][n][0] = acc[m][n][1] = acc[m][n][2] = acc[m][n][3] = 0.f;

  for (int k0 = 0; k0 < K; k0 += 32) {
    __syncthreads();   // guard previous iteration's fragment reads
    if constexpr (TM == 128) {
      // A: 128 rows x 32 k; thread -> row tid>>1, 32B (2 chunks) at (tid&1)*16
      const int r = tid >> 1, kp = (tid & 1) * 16;
      const uint4* ap = (const uint4*)(A + (size_t)(arow0 + bm + r) * K + k0 + kp);
      const uint4 v0 = ap[0], v1 = ap[1];
      *(uint4*)&As[r][kp]     = v0;
      *(uint4*)&As[r][kp + 8] = v1;
    } else {
      // A: 64 rows x 32 k; thread -> row tid>>2, 16B at (tid&3)*8
      const int r = tid >> 2, kp = (tid & 3) * 8;
      const uint4 v0 = *(const uint4*)(A + (size_t)(arow0 + bm + r) * K + k0 + kp);
      *(uint4*)&As[r][kp] = v0;
    }
    {
      // B: 128 rows x 32 k; thread -> row tid>>1, 32B at (tid&1)*16
      const int r = tid >> 1, kp = (tid & 1) * 16;
      const uint4* bp = (const uint4*)(Wt + (size_t)(bn + r) * K + k0 + kp);
      const uint4 v0 = bp[0], v1 = bp[1];
      *(uint4*)&Bs[r][kp]     = v0;
      *(uint4*)&Bs[r][kp + 8] = v1;
    }
    __syncthreads();
    f16x8 afr[MF], bf8[4];
#pragma unroll
    for (int m = 0; m < MF; ++m)
      afr[m] = *(const f16x8*)&As[wm * (TM / 2) + m * 16 + fr][g * 8];
#pragma unroll
    for (int n = 0; n < 4; ++n)
      bf8[n] = *(const f16x8*)&Bs[wn * 64 + n * 16 + fr][g * 8];
#pragma unroll
    for (int m = 0; m < MF; ++m)
#pragma unroll
      for (int n = 0; n < 4; ++n)
        acc[m][n] = __builtin_amdgcn_mfma_f32_16x16x32_f16(afr[m], bf8[n], acc[m][n], 0, 0, 0);
  }

  const int bfl = *bfp;
  const int rfl = (MODE == 4) ? *rfp : 0;
#pragma unroll
  for (int m = 0; m < MF; ++m) {
#pragma unroll
    for (int n = 0; n < 4; ++n) {
      const int gc = bn + wn * 64 + n * 16 + fr;
      const float bv = ldf(bias, gc, bfl);
#pragma unroll
      for (int e = 0; e < 4; ++e) {
        const int gr = erow0 + bm + wm * (TM / 2) + m * 16 + (lane >> 4) * 4 + e;
        float v = acc[m][n][e] + bv;
        if (MODE == 3) {
          outH[(size_t)gr * N + gc] = (_Float16)fmaxf(v, 0.f);
        } else if (MODE == 4) {
          v += ldf(res, (size_t)gr * 1024 + gc, rfl);
          outH[(size_t)gr * 1024 + gc] = (_Float16)v;
        } else {
          v += (float)resH[(size_t)gr * 1024 + gc];
          outF[(size_t)gr * 1024 + gc] = v;
        }
      }
    }
  }
}

// ---------------------------------------------------------------------------
// MFMA attention, SINGLE PASS with online row max (r6 version, 64 rows/block:
// best measured config -- 128-row variant regressed via occupancy loss).
// ---------------------------------------------------------------------------
#define ACAP 48

__global__ __launch_bounds__(256) void attn_mfma_k(
    const float* __restrict__ qb, const float* __restrict__ kb,
    const ushort* __restrict__ vb, ushort* __restrict__ ctx,
    unsigned* __restrict__ ovcount, unsigned* __restrict__ ovlist)
{
  __shared__ __align__(16) char smem[32768];
  ushort*   kpl  = (ushort*)smem;                 // [3][32][72] bf16 bits, 13824 B
  unsigned* cnt  = (unsigned*)(smem + 13824);     // [64]
  float*    mrow = (float*)(smem + 14080);        // [64]
  ushort*   cL   = (ushort*)(smem + 14336);       // [64][ACAP]  6144 B
  float*    LL   = (float*)(smem + 20480);        // [64][ACAP] 12288 B (end 32768)

  const int tid  = threadIdx.x;
  const int lane = tid & 63;
  const int wv   = tid >> 6;
  const int fr   = lane & 15, g = lane >> 4;
  const int h = blockIdx.y, b = blockIdx.z;
  const int s0 = blockIdx.x * 64;
  const size_t bh = (size_t)b * 16 + h;
  const float*  qh = qb + bh * (2048 * 64);
  const float*  kh = kb + bh * (2048 * 64);
  const ushort* vh = vb + bh * (2048 * 64);

  // ---- stage Q block (64 rows x 64 dims) as 3 bf16 planes (transient) ----
  {
    ushort* qs = (ushort*)smem;   // [3][64][72], plane stride 4608 elems
    const int r = tid >> 2, d0 = (tid & 3) * 16;
    const float4* qp = (const float4*)(qh + (size_t)(s0 + r) * 64 + d0);
    float tv[16];
#pragma unroll
    for (int u = 0; u < 4; ++u) {
      const float4 t = qp[u];
      tv[u*4]=t.x; tv[u*4+1]=t.y; tv[u*4+2]=t.z; tv[u*4+3]=t.w;
    }
    ushort p0[16], p1[16], p2[16];
#pragma unroll
    for (int u = 0; u < 16; ++u) {
      const float v = tv[u];
      const ushort a0 = f2b(v);
      const float r1 = v - b2f(a0);
      const ushort a1 = f2b(r1);
      const float r2 = r1 - b2f(a1);
      p0[u]=a0; p1[u]=a1; p2[u]=f2b(r2);
    }
    const int base = r * 72 + d0;
#pragma unroll
    for (int u = 0; u < 2; ++u) {
      *(uint4*)&qs[0*4608 + base + u*8] = *(uint4*)&p0[u*8];
      *(uint4*)&qs[1*4608 + base + u*8] = *(uint4*)&p1[u*8];
      *(uint4*)&qs[2*4608 + base + u*8] = *(uint4*)&p2[u*8];
    }
  }
  __syncthreads();
  bf16x8 af[3][2];
  {
    ushort* qs = (ushort*)smem;
    const int rb = (wv * 16 + fr) * 72 + g * 8;
#pragma unroll
    for (int p = 0; p < 3; ++p)
#pragma unroll
      for (int dg = 0; dg < 2; ++dg)
        af[p][dg] = *(bf16x8*)&qs[p*4608 + rb + dg*32];
  }
  __syncthreads();
  if (tid < 64) cnt[tid] = 0;

  float svv[4];
#pragma unroll
  for (int e = 0; e < 4; ++e) svv[e] = (float)(s0 + wv * 16 + g * 4 + e);

  float mloc[4] = {-3.0e38f, -3.0e38f, -3.0e38f, -3.0e38f};

  // -------- single pass: L, online row max, candidate collection --------
  for (int c0 = 0; c0 < 2048; c0 += 32) {
    __syncthreads();
    {   // stage 32 keys x 64 dims as 3 bf16 planes (once per tile)
      const int key = tid >> 3, d0 = (tid & 7) * 8;
      const float4* kp4 = (const float4*)(kh + (size_t)(c0 + key) * 64 + d0);
      const float4 t0 = kp4[0], t1 = kp4[1];
      float tv[8] = {t0.x,t0.y,t0.z,t0.w,t1.x,t1.y,t1.z,t1.w};
      ushort p0[8], p1[8], p2[8];
#pragma unroll
      for (int u = 0; u < 8; ++u) {
        const float v = tv[u];
        const ushort a0 = f2b(v);
        const float r1 = v - b2f(a0);
        const ushort a1 = f2b(r1);
        const float r2 = r1 - b2f(a1);
        p0[u]=a0; p1[u]=a1; p2[u]=f2b(r2);
      }
      const int base = key * 72 + d0;
      *(uint4*)&kpl[0*2304 + base] = *(uint4*)&p0[0];
      *(uint4*)&kpl[1*2304 + base] = *(uint4*)&p1[0];
      *(uint4*)&kpl[2*2304 + base] = *(uint4*)&p2[0];
    }
    __syncthreads();

    float Lv[2][4];
#pragma unroll
    for (int kg = 0; kg < 2; ++kg) {
      f32x4 a0v = {0.f,0.f,0.f,0.f}, a1v = {0.f,0.f,0.f,0.f}, a2v = {0.f,0.f,0.f,0.f};
#pragma unroll
      for (int dg = 0; dg < 2; ++dg) {
        const int rb = (kg * 16 + fr) * 72 + dg * 32 + g * 8;
        const bf16x8 b0 = *(bf16x8*)&kpl[0*2304 + rb];
        const bf16x8 b1 = *(bf16x8*)&kpl[1*2304 + rb];
        const bf16x8 b2 = *(bf16x8*)&kpl[2*2304 + rb];
        a0v = __builtin_amdgcn_mfma_f32_16x16x32_bf16(af[0][dg], b0, a0v, 0,0,0);
        a1v = __builtin_amdgcn_mfma_f32_16x16x32_bf16(af[0][dg], b1, a1v, 0,0,0);
        a2v = __builtin_amdgcn_mfma_f32_16x16x32_bf16(af[1][dg], b0, a2v, 0,0,0);
        a0v = __builtin_amdgcn_mfma_f32_16x16x32_bf16(af[1][dg], b1, a0v, 0,0,0);
        a1v = __builtin_amdgcn_mfma_f32_16x16x32_bf16(af[0][dg], b2, a1v, 0,0,0);
        a2v = __builtin_amdgcn_mfma_f32_16x16x32_bf16(af[2][dg], b0, a2v, 0,0,0);
      }
      const float cw = (float)(c0 + kg * 16 + fr);
#pragma unroll
      for (int e = 0; e < 4; ++e) {
        const float a = (a0v[e] + a1v[e]) + a2v[e];
        Lv[kg][e] = a * cw * svv[e];
      }
    }
    // per-row tile max across the 16 fr-lanes; update running max (uniform)
#pragma unroll
    for (int e = 0; e < 4; ++e) {
      float t = fmaxf(Lv[0][e], Lv[1][e]);
#pragma unroll
      for (int off = 1; off < 16; off <<= 1) t = fmaxf(t, __shfl_xor(t, off));
      mloc[e] = fmaxf(mloc[e], t);
    }
    // collect candidates vs the current running max
#pragma unroll
    for (int kg = 0; kg < 2; ++kg)
#pragma unroll
      for (int e = 0; e < 4; ++e) {
        if (Lv[kg][e] > mloc[e] - 80.f) {
          const int row = wv * 16 + g * 4 + e;
          const unsigned idx = atomicAdd(&cnt[row], 1u);
          if (idx < ACAP) {
            cL[row * ACAP + idx] = (ushort)(c0 + kg * 16 + fr);
            LL[row * ACAP + idx] = Lv[kg][e];
          }
        }
      }
  }
  // final row max (uniform across the 16 fr-lanes)
  if (fr == 0) {
#pragma unroll
    for (int e = 0; e < 4; ++e) mrow[wv * 16 + g * 4 + e] = mloc[e];
  }
  __syncthreads();

  // -------- phase 3: re-filter vs final max, exp + PV --------
  const int row = tid >> 2, seg = tid & 3;
  const unsigned n = cnt[row];
  const int gs = s0 + row;
  if (n > ACAP) {
    if (seg == 0) {
      const unsigned i = atomicAdd(ovcount, 1u);
      ovlist[i] = (unsigned)(bh * 2048 + gs);
    }
  } else {
    const float mf = mrow[row];
    float o[16];
#pragma unroll
    for (int u = 0; u < 16; ++u) o[u] = 0.f;
    float l = 0.f;
    for (unsigned i = 0; i < n; ++i) {
      const float d = LL[row * ACAP + i] - mf;
      if (d > -80.f) {
        const int c = cL[row * ACAP + i];
        const float p = expf(d);
        l += p;
        const uint4* vp = (const uint4*)(vh + (size_t)c * 64 + seg * 16);
        const uint4 t0 = vp[0], t1 = vp[1];
        const uint wds[8] = {t0.x,t0.y,t0.z,t0.w,t1.x,t1.y,t1.z,t1.w};
#pragma unroll
        for (int u = 0; u < 8; ++u) {
          o[u*2]   += p * b2f((ushort)(wds[u] & 0xffff));
          o[u*2+1] += p * b2f((ushort)(wds[u] >> 16));
        }
      }
    }
    const float inv = 1.f / l;
    ushort* op = ctx + (((size_t)b * 2048) + gs) * 1024 + h * 64 + seg * 16;
    uint pk[8];
#pragma unroll
    for (int u = 0; u < 8; ++u)
      pk[u] = (uint)f2h_u(o[2*u] * inv) | ((uint)f2h_u(o[2*u+1] * inv) << 16);
    *(uint4*)(op)     = make_uint4(pk[0], pk[1], pk[2], pk[3]);
    *(uint4*)(op + 8) = make_uint4(pk[4], pk[5], pk[6], pk[7]);
  }
}

// ---------------------------------------------------------------------------
// Key-parallel dense cleanup (unchanged): one block per flagged row.
// ---------------------------------------------------------------------------
__global__ __launch_bounds__(256) void attn_cleanup2_k(
    const float* __restrict__ qb, const float* __restrict__ kb,
    const ushort* __restrict__ vb, ushort* __restrict__ ctx,
    const unsigned* __restrict__ ovcount, const unsigned* __restrict__ ovlist)
{
  __shared__ float Ls[2048];
  __shared__ float osum[32][65];
  __shared__ float wm[4], wl[4];
  const unsigned count = *ovcount;
  const int tid = threadIdx.x;
  const int seg = tid & 7;
  const int kq  = tid >> 3;
  const int wave = tid >> 6;

  for (unsigned idx = blockIdx.x; idx < count; idx += gridDim.x) {
    const unsigned r = ovlist[idx];
    const int gs = (int)(r & 2047u);
    const size_t bh = (size_t)(r >> 11);
    const int b = (int)(bh >> 4), h = (int)(bh & 15);
    const float*  qh = qb + bh * (2048 * 64);
    const float*  kh = kb + bh * (2048 * 64);
    const ushort* vh = vb + bh * (2048 * 64);

    float q[8];
    {
      const float4* qp = (const float4*)(qh + (size_t)gs * 64 + seg * 8);
      const float4 t0 = qp[0], t1 = qp[1];
      q[0]=t0.x; q[1]=t0.y; q[2]=t0.z; q[3]=t0.w;
      q[4]=t1.x; q[5]=t1.y; q[6]=t1.z; q[7]=t1.w;
    }
    const float sq = (float)gs;

    float mloc = -3.0e38f;
    for (int it = 0; it < 64; ++it) {
      const int c = it * 32 + kq;
      const float4* kp = (const float4*)(kh + (size_t)c * 64 + seg * 8);
      const float4 a = kp[0], bb = kp[1];
      float dt = q[0]*a.x + q[1]*a.y + q[2]*a.z + q[3]*a.w
               + q[4]*bb.x + q[5]*bb.y + q[6]*bb.z + q[7]*bb.w;
      dt += __shfl_xor(dt, 1);
      dt += __shfl_xor(dt, 2);
      dt += __shfl_xor(dt, 4);
      const float L = dt * sq * (float)c;
      if (seg == 0) Ls[c] = L;
      mloc = fmaxf(mloc, L);
    }
    mloc = fmaxf(mloc, __shfl_xor(mloc, 8));
    mloc = fmaxf(mloc, __shfl_xor(mloc, 16));
    mloc = fmaxf(mloc, __shfl_xor(mloc, 32));
    if ((tid & 63) == 0) wm[wave] = mloc;
    __syncthreads();
    const float m = fmaxf(fmaxf(wm[0], wm[1]), fmaxf(wm[2], wm[3]));

    float o[8] = {0.f,0.f,0.f,0.f,0.f,0.f,0.f,0.f};
    float lloc = 0.f;
    for (int it = 0; it < 64; ++it) {
      const int c = it * 32 + kq;
      const float p = expf(Ls[c] - m);
      lloc += p;
      const uint4 vv = *(const uint4*)(vh + (size_t)c * 64 + seg * 8);
      o[0] += p * b2f((ushort)(vv.x & 0xffff)); o[1] += p * b2f((ushort)(vv.x >> 16));
      o[2] += p * b2f((ushort)(vv.y & 0xffff)); o[3] += p * b2f((ushort)(vv.y >> 16));
      o[4] += p * b2f((ushort)(vv.z & 0xffff)); o[5] += p * b2f((ushort)(vv.z >> 16));
      o[6] += p * b2f((ushort)(vv.w & 0xffff)); o[7] += p * b2f((ushort)(vv.w >> 16));
    }
    lloc += __shfl_xor(lloc, 8);
    lloc += __shfl_xor(lloc, 16);
    lloc += __shfl_xor(lloc, 32);
    if ((tid & 63) == 0) wl[wave] = lloc;
#pragma unroll
    for (int u = 0; u < 8; ++u) osum[kq][seg * 8 + u] = o[u];
    __syncthreads();
    const float l = (wl[0] + wl[1]) + (wl[2] + wl[3]);
    if (tid < 64) {
      float acc = 0.f;
#pragma unroll
      for (int k2 = 0; k2 < 32; ++k2) acc += osum[k2][tid];
      ctx[(((size_t)b * 2048) + gs) * 1024 + h * 64 + tid] = f2h_u(acc / l);
    }
    __syncthreads();
  }
}

// ---------------------------------------------------------------------------
// Fallback attention (38 MB path), unchanged.
// ---------------------------------------------------------------------------
template<int RPT, int OF16>
__global__ __launch_bounds__(256) void attn_k(
    const float* __restrict__ qb, const float* __restrict__ kb,
    const ushort* __restrict__ vb, ushort* __restrict__ ctx,
    int b0, size_t bstrF, size_t bstrU)
{
  __shared__ float kS[64][64];
  __shared__ float vS[64][64];
  const int tid = threadIdx.x;
  const int h  = blockIdx.y;
  const int bz = blockIdx.z;
  const int b  = b0 + bz;
  const float*  qh = qb + bstrF * bz + (size_t)h * 2048 * 64;
  const float*  kh = kb + bstrF * bz + (size_t)h * 2048 * 64;
  const ushort* vh = vb + bstrU * bz + (size_t)h * 2048 * 64;

  const int seg  = tid & 3;
  const int slot = tid >> 2;
  const int row0 = blockIdx.x * (64 * RPT) + slot * RPT;

  f32x2 qv[RPT][8], o[RPT][8];
  float m[RPT], l[RPT], sq[RPT];
#pragma unroll
  for (int i = 0; i < RPT; ++i) {
    const float4* qp = (const float4*)(qh + (size_t)(row0 + i) * 64 + seg * 16);
#pragma unroll
    for (int w = 0; w < 4; ++w) {
      const float4 t = qp[w];
      qv[i][2*w]   = f32x2{t.x, t.y};
      qv[i][2*w+1] = f32x2{t.z, t.w};
    }
    m[i] = -3.0e38f; l[i] = 0.f; sq[i] = (float)(row0 + i);
#pragma unroll
    for (int t = 0; t < 8; ++t) o[i][t] = f32x2{0.f, 0.f};
  }

  for (int c0 = 0; c0 < 2048; c0 += 64) {
    __syncthreads();
    {
      const int key = tid >> 2, sg = tid & 3;
      const float4* sp = (const float4*)(kh + (size_t)(c0 + key) * 64 + sg * 16);
      float4* dp = (float4*)&kS[key][sg * 16];
#pragma unroll
      for (int u = 0; u < 4; ++u) dp[u] = sp[u];
      const uint4* vp = (const uint4*)(vh + (size_t)(c0 + key) * 64 + sg * 16);
      float* vd = &vS[key][sg * 16];
#pragma unroll
      for (int u = 0; u < 2; ++u) {
        const uint4 t = vp[u];
        vd[u*8+0] = b2f((ushort)(t.x & 0xffff)); vd[u*8+1] = b2f((ushort)(t.x >> 16));
        vd[u*8+2] = b2f((ushort)(t.y & 0xffff)); vd[u*8+3] = b2f((ushort)(t.y >> 16));
        vd[u*8+4] = b2f((ushort)(t.z & 0xffff)); vd[u*8+5] = b2f((ushort)(t.z >> 16));
        vd[u*8+6] = b2f((ushort)(t.w & 0xffff)); vd[u*8+7] = b2f((ushort)(t.w >> 16));
      }
    }
    __syncthreads();
#pragma unroll 2
    for (int j = 0; j < 64; ++j) {
      const float4* kp = (const float4*)&kS[j][seg * 16];
      const float4 ka = kp[0], kb4 = kp[1], kc = kp[2], kd = kp[3];
      const f32x2 K0 = {ka.x, ka.y},  K1 = {ka.z, ka.w};
      const f32x2 K2 = {kb4.x, kb4.y}, K3 = {kb4.z, kb4.w};
      const f32x2 K4 = {kc.x, kc.y},  K5 = {kc.z, kc.w};
      const f32x2 K6 = {kd.x, kd.y},  K7 = {kd.z, kd.w};
      float dt[RPT];
#pragma unroll
      for (int i = 0; i < RPT; ++i) {
        f32x2 a2 = qv[i][0] * K0;
        a2 += qv[i][1] * K1;
        a2 += qv[i][2] * K2;
        a2 += qv[i][3] * K3;
        a2 += qv[i][4] * K4;
        a2 += qv[i][5] * K5;
        a2 += qv[i][6] * K6;
        a2 += qv[i][7] * K7;
        dt[i] = a2[0] + a2[1];
      }
#pragma unroll
      for (int i = 0; i < RPT; ++i) {
        dt[i] += __shfl_xor(dt[i], 1);
        dt[i] += __shfl_xor(dt[i], 2);
      }
      const float cc = (float)(c0 + j);
#pragma unroll
      for (int i = 0; i < RPT; ++i) {
        const float L = dt[i] * sq[i] * cc;
        const float d = L - m[i];
        if (d > 0.f) {
          const float r = expf(-d);
          l[i] = l[i] * r + 1.f;
          m[i] = L;
          const f32x2 r2 = {r, r};
          const float4* vp4 = (const float4*)&vS[j][seg * 16];
          const float4 va = vp4[0], vb4 = vp4[1], vc = vp4[2], vd4 = vp4[3];
          const f32x2 V[8] = {{va.x,va.y},{va.z,va.w},{vb4.x,vb4.y},{vb4.z,vb4.w},
                              {vc.x,vc.y},{vc.z,vc.w},{vd4.x,vd4.y},{vd4.z,vd4.w}};
#pragma unroll
          for (int t = 0; t < 8; ++t) o[i][t] = o[i][t] * r2 + V[t];
        } else if (d > -80.f) {
          const float p = expf(d);
          l[i] += p;
          const f32x2 p2 = {p, p};
          const float4* vp4 = (const float4*)&vS[j][seg * 16];
          const float4 va = vp4[0], vb4 = vp4[1], vc = vp4[2], vd4 = vp4[3];
          const f32x2 V[8] = {{va.x,va.y},{va.z,va.w},{vb4.x,vb4.y},{vb4.z,vb4.w},
                              {vc.x,vc.y},{vc.z,vc.w},{vd4.x,vd4.y},{vd4.z,vd4.w}};
#pragma unroll
          for (int t = 0; t < 8; ++t) o[i][t] += p2 * V[t];
        }
      }
    }
  }

#pragma unroll
  for (int i = 0; i < RPT; ++i) {
    const float inv = 1.f / l[i];
    ushort* op = ctx + (((size_t)b * 2048) + row0 + i) * 1024 + h * 64 + seg * 16;
    uint pk[8];
#pragma unroll
    for (int t2 = 0; t2 < 8; ++t2) {
      const uint lo = OF16 ? (uint)f2h_u(o[i][t2][0] * inv) : (uint)f2b(o[i][t2][0] * inv);
      const uint hi = OF16 ? (uint)f2h_u(o[i][t2][1] * inv) : (uint)f2b(o[i][t2][1] * inv);
      pk[t2] = lo | (hi << 16);
    }
    *(uint4*)(op)     = make_uint4(pk[0], pk[1], pk[2], pk[3]);
    *(uint4*)(op + 8) = make_uint4(pk[4], pk[5], pk[6], pk[7]);
  }
}

// ---------------------------------------------------------------------------
// LayerNorm 1024 cols, bf16 in -> bf16 out (fallback path).
// ---------------------------------------------------------------------------
__global__ __launch_bounds__(256) void ln_k(const ushort* __restrict__ y,
                                            const void* __restrict__ g,
                                            const void* __restrict__ be,
                                            const int* __restrict__ fp,
                                            ushort* __restrict__ out)
{
  const int row = blockIdx.x, tid = threadIdx.x;
  const int f = *fp;
  const ushort* p = y + (size_t)row * 1024;
  float v[4], s = 0.f, s2 = 0.f;
#pragma unroll
  for (int i = 0; i < 4; ++i) {
    const float x = b2f(p[tid + i * 256]);
    v[i] = x; s += x; s2 += x * x;
  }
#pragma unroll
  for (int off = 1; off < 64; off <<= 1) { s += __shfl_xor(s, off); s2 += __shfl_xor(s2, off); }
  __shared__ float red[8];
  const int wave = tid >> 6, lane = tid & 63;
  if (lane == 0) { red[wave] = s; red[4 + wave] = s2; }
  __syncthreads();
  s = red[0] + red[1] + red[2] + red[3];
  s2 = red[4] + red[5] + red[6] + red[7];
  const float mu = s * (1.f / 1024.f);
  const float var = s2 * (1.f / 1024.f) - mu * mu;
  const float rstd = rsqrtf(var + 1e-5f);
  ushort* o = out + (size_t)row * 1024;
#pragma unroll
  for (int i = 0; i < 4; ++i) {
    const int c = tid + i * 256;
    o[c] = f2b((v[i] - mu) * rstd * ldf(g, c, f) + ldf(be, c, f));
  }
}

// ---------------------------------------------------------------------------
// LayerNorm 1024 cols, f16 in -> f16 out (main path).
// ---------------------------------------------------------------------------
__global__ __launch_bounds__(256) void ln_h_k(const _Float16* __restrict__ y,
                                              const void* __restrict__ g,
                                              const void* __restrict__ be,
                                              const int* __restrict__ fp,
                                              _Float16* __restrict__ out)
{
  const int row = blockIdx.x, tid = threadIdx.x;
  const int f = *fp;
  const _Float16* p = y + (size_t)row * 1024;
  float v[4], s = 0.f, s2 = 0.f;
#pragma unroll
  for (int i = 0; i < 4; ++i) {
    const float x = (float)p[tid + i * 256];
    v[i] = x; s += x; s2 += x * x;
  }
#pragma unroll
  for (int off = 1; off < 64; off <<= 1) { s += __shfl_xor(s, off); s2 += __shfl_xor(s2, off); }
  __shared__ float red[8];
  const int wave = tid >> 6, lane = tid & 63;
  if (lane == 0) { red[wave] = s; red[4 + wave] = s2; }
  __syncthreads();
  s = red[0] + red[1] + red[2] + red[3];
  s2 = red[4] + red[5] + red[6] + red[7];
  const float mu = s * (1.f / 1024.f);
  const float var = s2 * (1.f / 1024.f) - mu * mu;
  const float rstd = rsqrtf(var + 1e-5f);
  _Float16* o = out + (size_t)row * 1024;
#pragma unroll
  for (int i = 0; i < 4; ++i) {
    const int c = tid + i * 256;
    o[c] = (_Float16)((v[i] - mu) * rstd * ldf(g, c, f) + ldf(be, c, f));
  }
}

// ---------------------------------------------------------------------------
// Final LayerNorm: fp32 in/out, in place on d_out.
// ---------------------------------------------------------------------------
__global__ __launch_bounds__(256) void ln_f32_k(float* __restrict__ y,
                                                const void* __restrict__ g,
                                                const void* __restrict__ be,
                                                const int* __restrict__ fp)
{
  const int row = blockIdx.x, tid = threadIdx.x;
  const int f = *fp;
  float* p = y + (size_t)row * 1024;
  float v[4], s = 0.f, s2 = 0.f;
#pragma unroll
  for (int i = 0; i < 4; ++i) {
    const float x = p[tid + i * 256];
    v[i] = x; s += x; s2 += x * x;
  }
#pragma unroll
  for (int off = 1; off < 64; off <<= 1) { s += __shfl_xor(s, off); s2 += __shfl_xor(s2, off); }
  __shared__ float red[8];
  const int wave = tid >> 6, lane = tid & 63;
  if (lane == 0) { red[wave] = s; red[4 + wave] = s2; }
  __syncthreads();
  s = red[0] + red[1] + red[2] + red[3];
  s2 = red[4] + red[5] + red[6] + red[7];
  const float mu = s * (1.f / 1024.f);
  const float var = s2 * (1.f / 1024.f) - mu * mu;
  const float rstd = rsqrtf(var + 1e-5f);
#pragma unroll
  for (int i = 0; i < 4; ++i) {
    const int c = tid + i * 256;
    p[c] = (v[i] - mu) * rstd * ldf(g, c, f) + ldf(be, c, f);
  }
}

// ---------------------------------------------------------------------------
extern "C" void kernel_launch(void* const* d_in, const int* in_sizes, int n_in,
                              void* d_out, int out_size, void* d_ws, size_t ws_size,
                              hipStream_t stream)
{
  const void* x  = d_in[0];
  const void* wq = d_in[1];  const void* bq = d_in[2];
  const void* wk = d_in[3];  const void* bk = d_in[4];
  const void* wv = d_in[5];  const void* bv = d_in[6];
  const void* wo = d_in[7];  const void* bo = d_in[8];
  const void* w1 = d_in[9];  const void* b1 = d_in[10];
  const void* w2 = d_in[11]; const void* b2 = d_in[12];
  const void* g1 = d_in[13]; const void* be1 = d_in[14];
  const void* g2 = d_in[15]; const void* be2 = d_in[16];
  float* outp = (float*)d_out;

  const size_t MB = 1048576;
  char* ws = (char*)d_ws;
  int*      flag    = (int*)(ws + 0);
  int*      zeroc   = (int*)(ws + 64);
  unsigned* ovcount = (unsigned*)(ws + 128);
  float*    wtab    = (float*)(ws + 256);

  detect_k<<<dim3(1), dim3(64), 0, stream>>>(x, flag);
  wtab_k<<<dim3(1), dim3(64), 0, stream>>>(wtab, zeroc, ovcount);

  const size_t QS = (size_t)16 * 2048 * 64;   // per-batch q/k/v element count

  if (ws_size >= (size_t)98 * MB) {
    // ---- main path (97.5 MB peak) ----
    float*     qb   = (float*)(ws + 1 * MB);
    float*     kb   = (float*)(ws + 33 * MB);
    ushort*    vb   = (ushort*)(ws + 65 * MB);
    ushort*    ctxh = (ushort*)(ws + 81 * MB);      // f16 bits
    unsigned*  ovlist = (unsigned*)(ws + 97 * MB);  // [131072] u32
    _Float16*  WoT  = (_Float16*)(ws + 65 * MB);
    _Float16*  W1T  = (_Float16*)(ws + 67 * MB);
    _Float16*  W2T  = (_Float16*)(ws + 75 * MB);
    _Float16*  y1h  = (_Float16*)(ws + 1 * MB);
    _Float16*  hh   = (_Float16*)(ws + 17 * MB);
    _Float16*  ffc  = (_Float16*)(ws + 33 * MB);

    // QKV: one fused dispatch per projection, M = 8192
    sgemm2<0><<<dim3(8, 64), 256, 0, stream>>>(x, flag, wq, bq, flag,
                                               nullptr, qb, wtab, 1024, 1024);
    sgemm2<1><<<dim3(8, 64), 256, 0, stream>>>(x, flag, wk, bk, flag,
                                               nullptr, kb, wtab, 1024, 1024);
    sgemm2<2><<<dim3(8, 64), 256, 0, stream>>>(x, flag, wv, bv, flag,
                                               vb, nullptr, wtab, 1024, 1024);

    // single-pass MFMA attention (64 rows/block) + key-parallel cleanup
    attn_mfma_k<<<dim3(32, 16, 4), 256, 0, stream>>>(qb, kb, vb, ctxh,
                                                     ovcount, ovlist);
    attn_cleanup2_k<<<dim3(8192), 256, 0, stream>>>(qb, kb, vb, ctxh,
                                                    ovcount, ovlist);

    cvt_wT_k<<<dim3(32, 32),  256, 0, stream>>>(wo, flag, WoT, 1024, 1024);
    cvt_wT_k<<<dim3(128, 32), 256, 0, stream>>>(w1, flag, W1T, 1024, 4096);

    hgemm<4, 128><<<dim3(8, 64), 256, 0, stream>>>((const _Float16*)ctxh, 0, WoT,
                                                   bo, flag, x, flag, nullptr,
                                                   y1h, nullptr, 1024, 1024, 0);
    cvt_wT_k<<<dim3(32, 128), 256, 0, stream>>>(w2, flag, W2T, 4096, 1024);

    ln_h_k<<<dim3(8192), 256, 0, stream>>>(y1h, g1, be1, flag, hh);

    for (int c = 0; c < 2; ++c) {
      hgemm<3, 128><<<dim3(32, 32), 256, 0, stream>>>(hh, c * 4096, W1T,
                                                      b1, flag, nullptr, zeroc, nullptr,
                                                      ffc, nullptr, 4096, 1024, 0);
      hgemm<5, 64><<<dim3(8, 64), 256, 0, stream>>>(ffc, 0, W2T,
                                                    b2, flag, nullptr, zeroc, hh,
                                                    nullptr, outp, 1024, 4096, c * 4096);
    }
    ln_f32_k<<<dim3(8192), 256, 0, stream>>>(outp, g2, be2, flag);
  } else {
    // ---- fallback: original 38 MB layout, bf16 everywhere ----
    float*  qb   = (float*)(ws + 1 * MB);
    float*  kb   = (float*)(ws + 9 * MB);
    ushort* vb   = (ushort*)(ws + 17 * MB);
    ushort* ctxb = (ushort*)(ws + 22 * MB);
    ushort* y1   = (ushort*)(ws + 1 * MB);
    ushort* hbuf = (ushort*)(ws + 22 * MB);
    ushort* ffc  = (ushort*)(ws + 1 * MB);

    for (int b = 0; b < 4; ++b) {
      sgemm<0><<<dim3(16, 32), 256, 0, stream>>>(x, flag, b * 2048, wq, bq, flag,
                                                 nullptr, nullptr, nullptr, qb, wtab,
                                                 1024, 1024, b * 2048);
      sgemm<1><<<dim3(16, 32), 256, 0, stream>>>(x, flag, b * 2048, wk, bk, flag,
                                                 nullptr, nullptr, nullptr, kb, wtab,
                                                 1024, 1024, b * 2048);
      sgemm<2><<<dim3(16, 32), 256, 0, stream>>>(x, flag, b * 2048, wv, bv, flag,
                                                 nullptr, nullptr, vb, nullptr, wtab,
                                                 1024, 1024, b * 2048);
      attn_k<1, 0><<<dim3(32, 16, 1), 256, 0, stream>>>(qb, kb, vb, ctxb, b, 0, 0);
    }

    sgemm<4><<<dim3(16, 128), 256, 0, stream>>>(ctxb, zeroc, 0, wo, bo, flag,
                                                x, flag, y1, nullptr, wtab,
                                                1024, 1024, 0);
    ln_k<<<dim3(8192), 256, 0, stream>>>(y1, g1, be1, flag, hbuf);
    for (int c = 0; c < 4; ++c) {
      sgemm<3><<<dim3(64, 32), 256, 0, stream>>>(hbuf, zeroc, c * 2048, w1, b1, flag,
                                                 nullptr, nullptr, ffc, nullptr, wtab,
                                                 4096, 1024, 0);
      sgemm<5><<<dim3(16, 32), 256, 0, stream>>>(ffc, zeroc, 0, w2, b2, flag,
                                                 hbuf, zeroc, nullptr, outp, wtab,
                                                 1024, 4096, c * 2048);
    }
    ln_f32_k<<<dim3(8192), 256, 0, stream>>>(outp, g2, be2, flag);
  }
}

// Round 9
// 1238.444 us; speedup vs baseline: 1.2642x; 1.2583x over previous
//
#include <hip/hip_runtime.h>

typedef _Float16 f16x8 __attribute__((ext_vector_type(8)));
typedef float    f32x4 __attribute__((ext_vector_type(4)));
typedef float    f32x2 __attribute__((ext_vector_type(2)));
typedef short    bf16x8 __attribute__((ext_vector_type(8)));

__device__ __forceinline__ float b2f(ushort u){
  union { float f; unsigned int i; } v; v.i = ((unsigned int)u) << 16; return v.f;
}
__device__ __forceinline__ ushort f2b(float f){
  union { float f; unsigned int i; } v; v.f = f;
  unsigned int r = (v.i + 0x7FFFu + ((v.i >> 16) & 1u)) >> 16;
  return (ushort)r;
}
__device__ __forceinline__ ushort f2h_u(float f){
  union { _Float16 h; ushort u; } v; v.h = (_Float16)f; return v.u;
}
// flag-typed load: f=1 -> fp32 array, f=0 -> bf16(ushort) array
__device__ __forceinline__ float ldf(const void* p, size_t i, int f){
  return f ? ((const float*)p)[i] : b2f(((const ushort*)p)[i]);
}
// 3-way bf16 split (RNE), identical to the attention kernel's split
__device__ __forceinline__ void split3(float v, ushort& a0, ushort& a1, ushort& a2){
  a0 = f2b(v);
  const float r1 = v - b2f(a0);
  a1 = f2b(r1);
  a2 = f2b(r1 - b2f(a1));
}

// ---------------------------------------------------------------------------
// Input storage detector on x: packed bf16 -> 0 ; fp32 (any) -> 1.
// ---------------------------------------------------------------------------
__global__ void detect_k(const void* __restrict__ x, int* __restrict__ flag)
{
  const int lane = threadIdx.x; // 64
  const ushort* p = (const ushort*)x;
  int wild = 0, zeven = 0;
#pragma unroll
  for (int j = 0; j < 8; ++j) {
    const int idx = lane * 8 + j;
    const ushort u = p[idx];
    if (((u >> 7) & 0xFF) >= 0xF1) ++wild;
    if (((idx & 1) == 0) && u == 0) ++zeven;
  }
#pragma unroll
  for (int off = 1; off < 64; off <<= 1) {
    wild += __shfl_xor(wild, off);
    zeven += __shfl_xor(zeven, off);
  }
  if (lane == 0) *flag = (wild >= 4 || zeven >= 128) ? 1 : 0;
}

// W table: logits = sq*sk * sum_d wt[d]*q_d*k_d  with 1/8 folded in.
// Also zeroes the overflow-row counter each launch.
__global__ void wtab_k(float* __restrict__ w, int* __restrict__ zeroc,
                       unsigned* __restrict__ ovc)
{
  const int d = threadIdx.x; // 64
  const int i = (d >> 1) & 15;
  const double F2 = pow(10000.0, -(double)i / 8.0);
  const double G2 = pow(10000.0, -(double)(2 * i + 1) / 16.0);
  w[d] = (float)((F2 + G2) * 0.125);
  if (d == 0) { *zeroc = 0; *ovc = 0u; }
}

// ---------------------------------------------------------------------------
// Weight convert + transpose: W[K][N] (flag-typed) -> Wt[N][K] f16.
// ---------------------------------------------------------------------------
__global__ __launch_bounds__(256) void cvt_wT_k(const void* __restrict__ W,
    const int* __restrict__ fp, _Float16* __restrict__ Wt, int K, int N)
{
  __shared__ float t[32][33];
  const int f = *fp;
  const int n0 = blockIdx.x * 32, k0 = blockIdx.y * 32;
  const int ln = threadIdx.x & 31, lr = threadIdx.x >> 5;
#pragma unroll
  for (int u = 0; u < 4; ++u) {
    const int kk = lr + u * 8;
    t[kk][ln] = ldf(W, (size_t)(k0 + kk) * N + n0 + ln, f);
  }
  __syncthreads();
#pragma unroll
  for (int u = 0; u < 4; ++u) {
    const int nn = lr + u * 8;
    Wt[(size_t)(n0 + nn) * K + k0 + ln] = (_Float16)t[ln][nn];
  }
}

// ---------------------------------------------------------------------------
// Weight convert + transpose + 3-way bf16 split:
// W[1024][1024] (flag-typed) -> Wt3[3][N=1024][K=1024] bf16 bits.
// ---------------------------------------------------------------------------
__global__ __launch_bounds__(256) void cvt_w3T_k(const void* __restrict__ W,
    const int* __restrict__ fp, ushort* __restrict__ Wt3)
{
  __shared__ float t[32][33];
  const int f = *fp;
  const int n0 = blockIdx.x * 32, k0 = blockIdx.y * 32;
  const int ln = threadIdx.x & 31, lr = threadIdx.x >> 5;
#pragma unroll
  for (int u = 0; u < 4; ++u) {
    const int kk = lr + u * 8;
    t[kk][ln] = ldf(W, (size_t)(k0 + kk) * 1024 + n0 + ln, f);
  }
  __syncthreads();
#pragma unroll
  for (int u = 0; u < 4; ++u) {
    const int nn = lr + u * 8;
    const float v = t[ln][nn];   // = W[k0+ln][n0+nn]
    ushort p0, p1, p2;
    split3(v, p0, p1, p2);
    const size_t o = (size_t)(n0 + nn) * 1024 + k0 + ln;
    Wt3[o]           = p0;
    Wt3[1048576 + o] = p1;
    Wt3[2097152 + o] = p2;
  }
}

// ---------------------------------------------------------------------------
// Fused q|k projection via split-bf16 (3x3, 6-product) MFMA, fp32-class.
// C[8192][2048] where cols 0..1023 -> q (scatter * wtab), 1024..2047 -> k.
// A = x (flag-typed), split to 3 bf16 planes in LDS per K-step.
// B = precomputed W3[3][N][K] bf16 planes, read directly from global (L2-hot).
// 128x128 tile, 4 waves (2x2), wave tile 64x64, 96 MFMA / wave / K-step.
// ---------------------------------------------------------------------------
__global__ __launch_bounds__(256) void sgemm_qk(
    const void* __restrict__ A, const int* __restrict__ afp,
    const ushort* __restrict__ W3q, const ushort* __restrict__ W3k,
    const void* __restrict__ bq, const void* __restrict__ bk,
    const int* __restrict__ wfp,
    float* __restrict__ qb, float* __restrict__ kbuf,
    const float* __restrict__ wtab)
{
  __shared__ ushort As3[3][128][32];
  const int tid = threadIdx.x;
  const int lane = tid & 63, w = tid >> 6;
  const int wm = w >> 1, wn = w & 1;
  const int fr = lane & 15, g = lane >> 4;
  const int bn = blockIdx.x * 128;        // 0..2047
  const int bm = blockIdx.y * 128;
  const int isK = bn >> 10;
  const ushort* W3 = isK ? W3k : W3q;
  const int bnl = bn & 1023;
  const int af = *afp;

  f32x4 acc[4][4];
#pragma unroll
  for (int m = 0; m < 4; ++m)
#pragma unroll
    for (int n = 0; n < 4; ++n)
      acc[m][n][0] = acc[m][n][1] = acc[m][n][2] = acc[m][n][3] = 0.f;

  for (int k0 = 0; k0 < 1024; k0 += 32) {
    __syncthreads();
    {   // stage A: 128 rows x 32 k, split into 3 bf16 planes
      const int row = tid >> 1, kk0 = (tid & 1) * 16;
      float tv[16];
      if (af) {
        const float4* p = (const float4*)((const float*)A + (size_t)(bm + row) * 1024 + k0 + kk0);
#pragma unroll
        for (int u = 0; u < 4; ++u) {
          const float4 t = p[u];
          tv[u*4]=t.x; tv[u*4+1]=t.y; tv[u*4+2]=t.z; tv[u*4+3]=t.w;
        }
      } else {
        const uint4* p = (const uint4*)((const ushort*)A + (size_t)(bm + row) * 1024 + k0 + kk0);
#pragma unroll
        for (int u = 0; u < 2; ++u) {
          const uint4 t = p[u];
          tv[u*8+0]=b2f((ushort)(t.x&0xffff)); tv[u*8+1]=b2f((ushort)(t.x>>16));
          tv[u*8+2]=b2f((ushort)(t.y&0xffff)); tv[u*8+3]=b2f((ushort)(t.y>>16));
          tv[u*8+4]=b2f((ushort)(t.z&0xffff)); tv[u*8+5]=b2f((ushort)(t.z>>16));
          tv[u*8+6]=b2f((ushort)(t.w&0xffff)); tv[u*8+7]=b2f((ushort)(t.w>>16));
        }
      }
      ushort p0[16], p1[16], p2[16];
#pragma unroll
      for (int u = 0; u < 16; ++u) split3(tv[u], p0[u], p1[u], p2[u]);
#pragma unroll
      for (int u = 0; u < 2; ++u) {
        *(uint4*)&As3[0][row][kk0 + u*8] = *(uint4*)&p0[u*8];
        *(uint4*)&As3[1][row][kk0 + u*8] = *(uint4*)&p1[u*8];
        *(uint4*)&As3[2][row][kk0 + u*8] = *(uint4*)&p2[u*8];
      }
    }
    __syncthreads();

    bf16x8 afr[3][4];
#pragma unroll
    for (int p = 0; p < 3; ++p)
#pragma unroll
      for (int m = 0; m < 4; ++m)
        afr[p][m] = *(const bf16x8*)&As3[p][wm*64 + m*16 + fr][g*8];

#pragma unroll
    for (int pb = 0; pb < 3; ++pb) {
      bf16x8 bfr[4];
#pragma unroll
      for (int n = 0; n < 4; ++n)
        bfr[n] = *(const bf16x8*)(W3 + (size_t)pb * 1048576 +
                                  (size_t)(bnl + wn*64 + n*16 + fr) * 1024 + k0 + g*8);
      const int npa = 3 - pb;   // products: (0,0),(1,0),(2,0),(0,1),(1,1),(0,2)
#pragma unroll
      for (int m = 0; m < 4; ++m)
#pragma unroll
        for (int n = 0; n < 4; ++n)
#pragma unroll
          for (int pa = 0; pa < 3; ++pa)
            if (pa < npa)
              acc[m][n] = __builtin_amdgcn_mfma_f32_16x16x32_bf16(
                              afr[pa][m], bfr[n], acc[m][n], 0, 0, 0);
    }
  }

  const int wf = *wfp;
#pragma unroll
  for (int m = 0; m < 4; ++m) {
#pragma unroll
    for (int n = 0; n < 4; ++n) {
      const int col = bnl + wn*64 + n*16 + fr;
      const float bv = ldf(isK ? bk : bq, col, wf);
      const int hh = col >> 6, dh = col & 63;
#pragma unroll
      for (int e = 0; e < 4; ++e) {
        const int gr = bm + wm*64 + m*16 + g*4 + e;
        const int b = gr >> 11, s = gr & 2047;
        const size_t idx = (size_t)b * 2097152 + (((size_t)hh * 2048) + s) * 64 + dh;
        const float v = acc[m][n][e] + bv;
        if (isK) kbuf[idx] = v;
        else     qb[idx]   = v * wtab[dh];
      }
    }
  }
}

// ---------------------------------------------------------------------------
// v projection via f16 MFMA (hgemm skeleton + flagged-A->f16 staging),
// scatter epilogue -> vb [b][h][s][d] bf16. v precision is dominated by its
// bf16 storage (4e-3) >> f16-GEMM error (~7e-4).
// ---------------------------------------------------------------------------
__global__ __launch_bounds__(256) void vgemm_k(
    const void* __restrict__ A, const int* __restrict__ afp,
    const _Float16* __restrict__ Wt,
    const void* __restrict__ bias, const int* __restrict__ bfp,
    ushort* __restrict__ outU)
{
  __shared__ _Float16 As[128][40];
  __shared__ _Float16 Bs[128][40];
  const int tid = threadIdx.x;
  const int lane = tid & 63;
  const int w = tid >> 6;
  const int wm = w >> 1, wn = w & 1;
  const int fr = lane & 15, g = lane >> 4;
  const int bn = blockIdx.x * 128, bm = blockIdx.y * 128;
  const int af = *afp;

  f32x4 acc[4][4];
#pragma unroll
  for (int m = 0; m < 4; ++m)
#pragma unroll
    for (int n = 0; n < 4; ++n)
      acc[m][n][0] = acc[m][n][1] = acc[m][n][2] = acc[m][n][3] = 0.f;

  for (int k0 = 0; k0 < 1024; k0 += 32) {
    __syncthreads();
    {   // A: 128 rows x 32 k, flagged fp32/bf16 -> f16
      const int r = tid >> 1, kp = (tid & 1) * 16;
      float tv[16];
      if (af) {
        const float4* p = (const float4*)((const float*)A + (size_t)(bm + r) * 1024 + k0 + kp);
#pragma unroll
        for (int u = 0; u < 4; ++u) {
          const float4 t = p[u];
          tv[u*4]=t.x; tv[u*4+1]=t.y; tv[u*4+2]=t.z; tv[u*4+3]=t.w;
        }
      } else {
        const uint4* p = (const uint4*)((const ushort*)A + (size_t)(bm + r) * 1024 + k0 + kp);
#pragma unroll
        for (int u = 0; u < 2; ++u) {
          const uint4 t = p[u];
          tv[u*8+0]=b2f((ushort)(t.x&0xffff)); tv[u*8+1]=b2f((ushort)(t.x>>16));
          tv[u*8+2]=b2f((ushort)(t.y&0xffff)); tv[u*8+3]=b2f((ushort)(t.y>>16));
          tv[u*8+4]=b2f((ushort)(t.z&0xffff)); tv[u*8+5]=b2f((ushort)(t.z>>16));
          tv[u*8+6]=b2f((ushort)(t.w&0xffff)); tv[u*8+7]=b2f((ushort)(t.w>>16));
        }
      }
      _Float16 hv[16];
#pragma unroll
      for (int u = 0; u < 16; ++u) hv[u] = (_Float16)tv[u];
      *(uint4*)&As[r][kp]     = *(uint4*)&hv[0];
      *(uint4*)&As[r][kp + 8] = *(uint4*)&hv[8];
    }
    {   // B: 128 rows x 32 k from Wt f16
      const int r = tid >> 1, kp = (tid & 1) * 16;
      const uint4* bp = (const uint4*)(Wt + (size_t)(bn + r) * 1024 + k0 + kp);
      const uint4 v0 = bp[0], v1 = bp[1];
      *(uint4*)&Bs[r][kp]     = v0;
      *(uint4*)&Bs[r][kp + 8] = v1;
    }
    __syncthreads();
    f16x8 afr[4], bf8[4];
#pragma unroll
    for (int m = 0; m < 4; ++m)
      afr[m] = *(const f16x8*)&As[wm * 64 + m * 16 + fr][g * 8];
#pragma unroll
    for (int n = 0; n < 4; ++n)
      bf8[n] = *(const f16x8*)&Bs[wn * 64 + n * 16 + fr][g * 8];
#pragma unroll
    for (int m = 0; m < 4; ++m)
#pragma unroll
      for (int n = 0; n < 4; ++n)
        acc[m][n] = __builtin_amdgcn_mfma_f32_16x16x32_f16(afr[m], bf8[n], acc[m][n], 0, 0, 0);
  }

  const int bfl = *bfp;
#pragma unroll
  for (int m = 0; m < 4; ++m) {
#pragma unroll
    for (int n = 0; n < 4; ++n) {
      const int gc = bn + wn * 64 + n * 16 + fr;
      const float bv = ldf(bias, gc, bfl);
      const int hh = gc >> 6, dh = gc & 63;
#pragma unroll
      for (int e = 0; e < 4; ++e) {
        const int gr = bm + wm * 64 + m * 16 + g * 4 + e;
        const int b = gr >> 11, s = gr & 2047;
        const size_t idx = (size_t)b * 2097152 + (((size_t)hh * 2048) + s) * 64 + dh;
        outU[idx] = f2b(acc[m][n][e] + bv);
      }
    }
  }
}

// ---------------------------------------------------------------------------
// fp32 VALU GEMM (fallback path, unchanged).
// ---------------------------------------------------------------------------
template<int MODE>
__global__ __launch_bounds__(256) void sgemm(
    const void* __restrict__ A, const int* __restrict__ afp, int arow0,
    const void* __restrict__ W, const void* __restrict__ bias,
    const int* __restrict__ wfp,
    const void* __restrict__ res, const int* __restrict__ rfp,
    ushort* __restrict__ outU, float* __restrict__ outF,
    const float* __restrict__ wtab,
    int N, int K, int erow0)
{
  __shared__ float As[64][17];
  __shared__ float Ws[16][65];
  const int tid = threadIdx.x;
  const int tx = tid & 15, ty = tid >> 4;
  const int bn = blockIdx.x * 64, bm = blockIdx.y * 64;
  const int af = *afp, wf = *wfp;

  float acc[4][4] = {};

  for (int k0 = 0; k0 < K; k0 += 16) {
    __syncthreads();
#pragma unroll
    for (int u = 0; u < 4; ++u) {
      const int idx = tid * 4 + u;
      const int row = idx >> 4, kk = idx & 15;
      As[row][kk] = ldf(A, (size_t)(arow0 + bm + row) * K + k0 + kk, af);
    }
#pragma unroll
    for (int u = 0; u < 4; ++u) {
      const int idx = tid * 4 + u;
      const int kk = idx >> 6, col = idx & 63;
      Ws[kk][col] = ldf(W, (size_t)(k0 + kk) * N + bn + col, wf);
    }
    __syncthreads();
#pragma unroll
    for (int kk = 0; kk < 16; ++kk) {
      float ar[4], wr[4];
#pragma unroll
      for (int i = 0; i < 4; ++i) ar[i] = As[ty * 4 + i][kk];
#pragma unroll
      for (int j = 0; j < 4; ++j) wr[j] = Ws[kk][tx * 4 + j];
#pragma unroll
      for (int i = 0; i < 4; ++i)
#pragma unroll
        for (int j = 0; j < 4; ++j) acc[i][j] += ar[i] * wr[j];
    }
  }

  const int rf = (MODE >= 4) ? *rfp : 0;
#pragma unroll
  for (int i = 0; i < 4; ++i) {
    const int gr = erow0 + bm + ty * 4 + i;
#pragma unroll
    for (int j = 0; j < 4; ++j) {
      const int gc = bn + tx * 4 + j;
      float v = acc[i][j] + ldf(bias, gc, wf);
      if (MODE == 0) {
        const int hh = gc >> 6, dh = gc & 63, s = gr & 2047;
        outF[(((size_t)hh * 2048) + s) * 64 + dh] = v * wtab[dh];
      } else if (MODE == 1) {
        const int hh = gc >> 6, dh = gc & 63, s = gr & 2047;
        outF[(((size_t)hh * 2048) + s) * 64 + dh] = v;
      } else if (MODE == 2) {
        const int hh = gc >> 6, dh = gc & 63, s = gr & 2047;
        outU[(((size_t)hh * 2048) + s) * 64 + dh] = f2b(v);
      } else if (MODE == 3) {
        outU[(size_t)gr * N + gc] = f2b(fmaxf(v, 0.f));
      } else if (MODE == 4) {
        v += ldf(res, (size_t)gr * 1024 + gc, rf);
        outU[(size_t)gr * 1024 + gc] = f2b(v);
      } else {
        v += ldf(res, (size_t)gr * 1024 + gc, rf);
        outF[(size_t)gr * 1024 + gc] = v;
      }
    }
  }
}

// ---------------------------------------------------------------------------
// f16 MFMA GEMM (r8 version, unchanged).
// ---------------------------------------------------------------------------
template<int MODE, int TM>
__global__ __launch_bounds__(256) void hgemm(
    const _Float16* __restrict__ A, int arow0,
    const _Float16* __restrict__ Wt,
    const void* __restrict__ bias, const int* __restrict__ bfp,
    const void* __restrict__ res, const int* __restrict__ rfp,
    const _Float16* __restrict__ resH,
    _Float16* __restrict__ outH, float* __restrict__ outF,
    int N, int K, int erow0)
{
  constexpr int MF = TM / 32;
  __shared__ _Float16 As[TM][40];
  __shared__ _Float16 Bs[128][40];
  const int tid = threadIdx.x;
  const int lane = tid & 63;
  const int w = tid >> 6;
  const int wm = w >> 1, wn = w & 1;
  const int fr = lane & 15, g = lane >> 4;
  const int bn = blockIdx.x * 128, bm = blockIdx.y * TM;

  f32x4 acc[MF][4];
#pragma unroll
  for (int m = 0; m < MF; ++m)
#pragma unroll
    for (int n = 0; n < 4; ++n)
      acc[m][n][0] = acc[m][n][1] = acc[m][n][2] = acc[m][n][3] = 0.f;

  for (int k0 = 0; k0 < K; k0 += 32) {
    __syncthreads();
    if constexpr (TM == 128) {
      const int r = tid >> 1, kp = (tid & 1) * 16;
      const uint4* ap = (const uint4*)(A + (size_t)(arow0 + bm + r) * K + k0 + kp);
      const uint4 v0 = ap[0], v1 = ap[1];
      *(uint4*)&As[r][kp]     = v0;
      *(uint4*)&As[r][kp + 8] = v1;
    } else {
      const int r = tid >> 2, kp = (tid & 3) * 8;
      const uint4 v0 = *(const uint4*)(A + (size_t)(arow0 + bm + r) * K + k0 + kp);
      *(uint4*)&As[r][kp] = v0;
    }
    {
      const int r = tid >> 1, kp = (tid & 1) * 16;
      const uint4* bp = (const uint4*)(Wt + (size_t)(bn + r) * K + k0 + kp);
      const uint4 v0 = bp[0], v1 = bp[1];
      *(uint4*)&Bs[r][kp]     = v0;
      *(uint4*)&Bs[r][kp + 8] = v1;
    }
    __syncthreads();
    f16x8 afr[MF], bf8[4];
#pragma unroll
    for (int m = 0; m < MF; ++m)
      afr[m] = *(const f16x8*)&As[wm * (TM / 2) + m * 16 + fr][g * 8];
#pragma unroll
    for (int n = 0; n < 4; ++n)
      bf8[n] = *(const f16x8*)&Bs[wn * 64 + n * 16 + fr][g * 8];
#pragma unroll
    for (int m = 0; m < MF; ++m)
#pragma unroll
      for (int n = 0; n < 4; ++n)
        acc[m][n] = __builtin_amdgcn_mfma_f32_16x16x32_f16(afr[m], bf8[n], acc[m][n], 0, 0, 0);
  }

  const int bfl = *bfp;
  const int rfl = (MODE == 4) ? *rfp : 0;
#pragma unroll
  for (int m = 0; m < MF; ++m) {
#pragma unroll
    for (int n = 0; n < 4; ++n) {
      const int gc = bn + wn * 64 + n * 16 + fr;
      const float bv = ldf(bias, gc, bfl);
#pragma unroll
      for (int e = 0; e < 4; ++e) {
        const int gr = erow0 + bm + wm * (TM / 2) + m * 16 + (lane >> 4) * 4 + e;
        float v = acc[m][n][e] + bv;
        if (MODE == 3) {
          outH[(size_t)gr * N + gc] = (_Float16)fmaxf(v, 0.f);
        } else if (MODE == 4) {
          v += ldf(res, (size_t)gr * 1024 + gc, rfl);
          outH[(size_t)gr * 1024 + gc] = (_Float16)v;
        } else {
          v += (float)resH[(size_t)gr * 1024 + gc];
          outF[(size_t)gr * 1024 + gc] = v;
        }
      }
    }
  }
}

// ---------------------------------------------------------------------------
// MFMA attention, SINGLE PASS with online row max (r6/r8 version, 64 rows).
// ---------------------------------------------------------------------------
#define ACAP 48

__global__ __launch_bounds__(256) void attn_mfma_k(
    const float* __restrict__ qb, const float* __restrict__ kb,
    const ushort* __restrict__ vb, ushort* __restrict__ ctx,
    unsigned* __restrict__ ovcount, unsigned* __restrict__ ovlist)
{
  __shared__ __align__(16) char smem[32768];
  ushort*   kpl  = (ushort*)smem;                 // [3][32][72] bf16 bits, 13824 B
  unsigned* cnt  = (unsigned*)(smem + 13824);     // [64]
  float*    mrow = (float*)(smem + 14080);        // [64]
  ushort*   cL   = (ushort*)(smem + 14336);       // [64][ACAP]  6144 B
  float*    LL   = (float*)(smem + 20480);        // [64][ACAP] 12288 B (end 32768)

  const int tid  = threadIdx.x;
  const int lane = tid & 63;
  const int wv   = tid >> 6;
  const int fr   = lane & 15, g = lane >> 4;
  const int h = blockIdx.y, b = blockIdx.z;
  const int s0 = blockIdx.x * 64;
  const size_t bh = (size_t)b * 16 + h;
  const float*  qh = qb + bh * (2048 * 64);
  const float*  kh = kb + bh * (2048 * 64);
  const ushort* vh = vb + bh * (2048 * 64);

  // ---- stage Q block (64 rows x 64 dims) as 3 bf16 planes (transient) ----
  {
    ushort* qs = (ushort*)smem;   // [3][64][72], plane stride 4608 elems
    const int r = tid >> 2, d0 = (tid & 3) * 16;
    const float4* qp = (const float4*)(qh + (size_t)(s0 + r) * 64 + d0);
    float tv[16];
#pragma unroll
    for (int u = 0; u < 4; ++u) {
      const float4 t = qp[u];
      tv[u*4]=t.x; tv[u*4+1]=t.y; tv[u*4+2]=t.z; tv[u*4+3]=t.w;
    }
    ushort p0[16], p1[16], p2[16];
#pragma unroll
    for (int u = 0; u < 16; ++u) split3(tv[u], p0[u], p1[u], p2[u]);
    const int base = r * 72 + d0;
#pragma unroll
    for (int u = 0; u < 2; ++u) {
      *(uint4*)&qs[0*4608 + base + u*8] = *(uint4*)&p0[u*8];
      *(uint4*)&qs[1*4608 + base + u*8] = *(uint4*)&p1[u*8];
      *(uint4*)&qs[2*4608 + base + u*8] = *(uint4*)&p2[u*8];
    }
  }
  __syncthreads();
  bf16x8 af[3][2];
  {
    ushort* qs = (ushort*)smem;
    const int rb = (wv * 16 + fr) * 72 + g * 8;
#pragma unroll
    for (int p = 0; p < 3; ++p)
#pragma unroll
      for (int dg = 0; dg < 2; ++dg)
        af[p][dg] = *(bf16x8*)&qs[p*4608 + rb + dg*32];
  }
  __syncthreads();
  if (tid < 64) cnt[tid] = 0;

  float svv[4];
#pragma unroll
  for (int e = 0; e < 4; ++e) svv[e] = (float)(s0 + wv * 16 + g * 4 + e);

  float mloc[4] = {-3.0e38f, -3.0e38f, -3.0e38f, -3.0e38f};

  // -------- single pass: L, online row max, candidate collection --------
  for (int c0 = 0; c0 < 2048; c0 += 32) {
    __syncthreads();
    {   // stage 32 keys x 64 dims as 3 bf16 planes (once per tile)
      const int key = tid >> 3, d0 = (tid & 7) * 8;
      const float4* kp4 = (const float4*)(kh + (size_t)(c0 + key) * 64 + d0);
      const float4 t0 = kp4[0], t1 = kp4[1];
      float tv[8] = {t0.x,t0.y,t0.z,t0.w,t1.x,t1.y,t1.z,t1.w};
      ushort p0[8], p1[8], p2[8];
#pragma unroll
      for (int u = 0; u < 8; ++u) split3(tv[u], p0[u], p1[u], p2[u]);
      const int base = key * 72 + d0;
      *(uint4*)&kpl[0*2304 + base] = *(uint4*)&p0[0];
      *(uint4*)&kpl[1*2304 + base] = *(uint4*)&p1[0];
      *(uint4*)&kpl[2*2304 + base] = *(uint4*)&p2[0];
    }
    __syncthreads();

    float Lv[2][4];
#pragma unroll
    for (int kg = 0; kg < 2; ++kg) {
      f32x4 a0v = {0.f,0.f,0.f,0.f}, a1v = {0.f,0.f,0.f,0.f}, a2v = {0.f,0.f,0.f,0.f};
#pragma unroll
      for (int dg = 0; dg < 2; ++dg) {
        const int rb = (kg * 16 + fr) * 72 + dg * 32 + g * 8;
        const bf16x8 b0 = *(bf16x8*)&kpl[0*2304 + rb];
        const bf16x8 b1 = *(bf16x8*)&kpl[1*2304 + rb];
        const bf16x8 b2 = *(bf16x8*)&kpl[2*2304 + rb];
        a0v = __builtin_amdgcn_mfma_f32_16x16x32_bf16(af[0][dg], b0, a0v, 0,0,0);
        a1v = __builtin_amdgcn_mfma_f32_16x16x32_bf16(af[0][dg], b1, a1v, 0,0,0);
        a2v = __builtin_amdgcn_mfma_f32_16x16x32_bf16(af[1][dg], b0, a2v, 0,0,0);
        a0v = __builtin_amdgcn_mfma_f32_16x16x32_bf16(af[1][dg], b1, a0v, 0,0,0);
        a1v = __builtin_amdgcn_mfma_f32_16x16x32_bf16(af[0][dg], b2, a1v, 0,0,0);
        a2v = __builtin_amdgcn_mfma_f32_16x16x32_bf16(af[2][dg], b0, a2v, 0,0,0);
      }
      const float cw = (float)(c0 + kg * 16 + fr);
#pragma unroll
      for (int e = 0; e < 4; ++e) {
        const float a = (a0v[e] + a1v[e]) + a2v[e];
        Lv[kg][e] = a * cw * svv[e];
      }
    }
    // per-row tile max across the 16 fr-lanes; update running max (uniform)
#pragma unroll
    for (int e = 0; e < 4; ++e) {
      float t = fmaxf(Lv[0][e], Lv[1][e]);
#pragma unroll
      for (int off = 1; off < 16; off <<= 1) t = fmaxf(t, __shfl_xor(t, off));
      mloc[e] = fmaxf(mloc[e], t);
    }
    // collect candidates vs the current running max
#pragma unroll
    for (int kg = 0; kg < 2; ++kg)
#pragma unroll
      for (int e = 0; e < 4; ++e) {
        if (Lv[kg][e] > mloc[e] - 80.f) {
          const int row = wv * 16 + g * 4 + e;
          const unsigned idx = atomicAdd(&cnt[row], 1u);
          if (idx < ACAP) {
            cL[row * ACAP + idx] = (ushort)(c0 + kg * 16 + fr);
            LL[row * ACAP + idx] = Lv[kg][e];
          }
        }
      }
  }
  // final row max (uniform across the 16 fr-lanes)
  if (fr == 0) {
#pragma unroll
    for (int e = 0; e < 4; ++e) mrow[wv * 16 + g * 4 + e] = mloc[e];
  }
  __syncthreads();

  // -------- phase 3: re-filter vs final max, exp + PV --------
  const int row = tid >> 2, seg = tid & 3;
  const unsigned n = cnt[row];
  const int gs = s0 + row;
  if (n > ACAP) {
    if (seg == 0) {
      const unsigned i = atomicAdd(ovcount, 1u);
      ovlist[i] = (unsigned)(bh * 2048 + gs);
    }
  } else {
    const float mf = mrow[row];
    float o[16];
#pragma unroll
    for (int u = 0; u < 16; ++u) o[u] = 0.f;
    float l = 0.f;
    for (unsigned i = 0; i < n; ++i) {
      const float d = LL[row * ACAP + i] - mf;
      if (d > -80.f) {
        const int c = cL[row * ACAP + i];
        const float p = expf(d);
        l += p;
        const uint4* vp = (const uint4*)(vh + (size_t)c * 64 + seg * 16);
        const uint4 t0 = vp[0], t1 = vp[1];
        const uint wds[8] = {t0.x,t0.y,t0.z,t0.w,t1.x,t1.y,t1.z,t1.w};
#pragma unroll
        for (int u = 0; u < 8; ++u) {
          o[u*2]   += p * b2f((ushort)(wds[u] & 0xffff));
          o[u*2+1] += p * b2f((ushort)(wds[u] >> 16));
        }
      }
    }
    const float inv = 1.f / l;
    ushort* op = ctx + (((size_t)b * 2048) + gs) * 1024 + h * 64 + seg * 16;
    uint pk[8];
#pragma unroll
    for (int u = 0; u < 8; ++u)
      pk[u] = (uint)f2h_u(o[2*u] * inv) | ((uint)f2h_u(o[2*u+1] * inv) << 16);
    *(uint4*)(op)     = make_uint4(pk[0], pk[1], pk[2], pk[3]);
    *(uint4*)(op + 8) = make_uint4(pk[4], pk[5], pk[6], pk[7]);
  }
}

// ---------------------------------------------------------------------------
// Key-parallel dense cleanup (unchanged): one block per flagged row.
// ---------------------------------------------------------------------------
__global__ __launch_bounds__(256) void attn_cleanup2_k(
    const float* __restrict__ qb, const float* __restrict__ kb,
    const ushort* __restrict__ vb, ushort* __restrict__ ctx,
    const unsigned* __restrict__ ovcount, const unsigned* __restrict__ ovlist)
{
  __shared__ float Ls[2048];
  __shared__ float osum[32][65];
  __shared__ float wm[4], wl[4];
  const unsigned count = *ovcount;
  const int tid = threadIdx.x;
  const int seg = tid & 7;
  const int kq  = tid >> 3;
  const int wave = tid >> 6;

  for (unsigned idx = blockIdx.x; idx < count; idx += gridDim.x) {
    const unsigned r = ovlist[idx];
    const int gs = (int)(r & 2047u);
    const size_t bh = (size_t)(r >> 11);
    const int b = (int)(bh >> 4), h = (int)(bh & 15);
    const float*  qh = qb + bh * (2048 * 64);
    const float*  kh = kb + bh * (2048 * 64);
    const ushort* vh = vb + bh * (2048 * 64);

    float q[8];
    {
      const float4* qp = (const float4*)(qh + (size_t)gs * 64 + seg * 8);
      const float4 t0 = qp[0], t1 = qp[1];
      q[0]=t0.x; q[1]=t0.y; q[2]=t0.z; q[3]=t0.w;
      q[4]=t1.x; q[5]=t1.y; q[6]=t1.z; q[7]=t1.w;
    }
    const float sq = (float)gs;

    float mloc = -3.0e38f;
    for (int it = 0; it < 64; ++it) {
      const int c = it * 32 + kq;
      const float4* kp = (const float4*)(kh + (size_t)c * 64 + seg * 8);
      const float4 a = kp[0], bb = kp[1];
      float dt = q[0]*a.x + q[1]*a.y + q[2]*a.z + q[3]*a.w
               + q[4]*bb.x + q[5]*bb.y + q[6]*bb.z + q[7]*bb.w;
      dt += __shfl_xor(dt, 1);
      dt += __shfl_xor(dt, 2);
      dt += __shfl_xor(dt, 4);
      const float L = dt * sq * (float)c;
      if (seg == 0) Ls[c] = L;
      mloc = fmaxf(mloc, L);
    }
    mloc = fmaxf(mloc, __shfl_xor(mloc, 8));
    mloc = fmaxf(mloc, __shfl_xor(mloc, 16));
    mloc = fmaxf(mloc, __shfl_xor(mloc, 32));
    if ((tid & 63) == 0) wm[wave] = mloc;
    __syncthreads();
    const float m = fmaxf(fmaxf(wm[0], wm[1]), fmaxf(wm[2], wm[3]));

    float o[8] = {0.f,0.f,0.f,0.f,0.f,0.f,0.f,0.f};
    float lloc = 0.f;
    for (int it = 0; it < 64; ++it) {
      const int c = it * 32 + kq;
      const float p = expf(Ls[c] - m);
      lloc += p;
      const uint4 vv = *(const uint4*)(vh + (size_t)c * 64 + seg * 8);
      o[0] += p * b2f((ushort)(vv.x & 0xffff)); o[1] += p * b2f((ushort)(vv.x >> 16));
      o[2] += p * b2f((ushort)(vv.y & 0xffff)); o[3] += p * b2f((ushort)(vv.y >> 16));
      o[4] += p * b2f((ushort)(vv.z & 0xffff)); o[5] += p * b2f((ushort)(vv.z >> 16));
      o[6] += p * b2f((ushort)(vv.w & 0xffff)); o[7] += p * b2f((ushort)(vv.w >> 16));
    }
    lloc += __shfl_xor(lloc, 8);
    lloc += __shfl_xor(lloc, 16);
    lloc += __shfl_xor(lloc, 32);
    if ((tid & 63) == 0) wl[wave] = lloc;
#pragma unroll
    for (int u = 0; u < 8; ++u) osum[kq][seg * 8 + u] = o[u];
    __syncthreads();
    const float l = (wl[0] + wl[1]) + (wl[2] + wl[3]);
    if (tid < 64) {
      float acc = 0.f;
#pragma unroll
      for (int k2 = 0; k2 < 32; ++k2) acc += osum[k2][tid];
      ctx[(((size_t)b * 2048) + gs) * 1024 + h * 64 + tid] = f2h_u(acc / l);
    }
    __syncthreads();
  }
}

// ---------------------------------------------------------------------------
// Fallback attention (38 MB path), unchanged.
// ---------------------------------------------------------------------------
template<int RPT, int OF16>
__global__ __launch_bounds__(256) void attn_k(
    const float* __restrict__ qb, const float* __restrict__ kb,
    const ushort* __restrict__ vb, ushort* __restrict__ ctx,
    int b0, size_t bstrF, size_t bstrU)
{
  __shared__ float kS[64][64];
  __shared__ float vS[64][64];
  const int tid = threadIdx.x;
  const int h  = blockIdx.y;
  const int bz = blockIdx.z;
  const int b  = b0 + bz;
  const float*  qh = qb + bstrF * bz + (size_t)h * 2048 * 64;
  const float*  kh = kb + bstrF * bz + (size_t)h * 2048 * 64;
  const ushort* vh = vb + bstrU * bz + (size_t)h * 2048 * 64;

  const int seg  = tid & 3;
  const int slot = tid >> 2;
  const int row0 = blockIdx.x * (64 * RPT) + slot * RPT;

  f32x2 qv[RPT][8], o[RPT][8];
  float m[RPT], l[RPT], sq[RPT];
#pragma unroll
  for (int i = 0; i < RPT; ++i) {
    const float4* qp = (const float4*)(qh + (size_t)(row0 + i) * 64 + seg * 16);
#pragma unroll
    for (int w = 0; w < 4; ++w) {
      const float4 t = qp[w];
      qv[i][2*w]   = f32x2{t.x, t.y};
      qv[i][2*w+1] = f32x2{t.z, t.w};
    }
    m[i] = -3.0e38f; l[i] = 0.f; sq[i] = (float)(row0 + i);
#pragma unroll
    for (int t = 0; t < 8; ++t) o[i][t] = f32x2{0.f, 0.f};
  }

  for (int c0 = 0; c0 < 2048; c0 += 64) {
    __syncthreads();
    {
      const int key = tid >> 2, sg = tid & 3;
      const float4* sp = (const float4*)(kh + (size_t)(c0 + key) * 64 + sg * 16);
      float4* dp = (float4*)&kS[key][sg * 16];
#pragma unroll
      for (int u = 0; u < 4; ++u) dp[u] = sp[u];
      const uint4* vp = (const uint4*)(vh + (size_t)(c0 + key) * 64 + sg * 16);
      float* vd = &vS[key][sg * 16];
#pragma unroll
      for (int u = 0; u < 2; ++u) {
        const uint4 t = vp[u];
        vd[u*8+0] = b2f((ushort)(t.x & 0xffff)); vd[u*8+1] = b2f((ushort)(t.x >> 16));
        vd[u*8+2] = b2f((ushort)(t.y & 0xffff)); vd[u*8+3] = b2f((ushort)(t.y >> 16));
        vd[u*8+4] = b2f((ushort)(t.z & 0xffff)); vd[u*8+5] = b2f((ushort)(t.z >> 16));
        vd[u*8+6] = b2f((ushort)(t.w & 0xffff)); vd[u*8+7] = b2f((ushort)(t.w >> 16));
      }
    }
    __syncthreads();
#pragma unroll 2
    for (int j = 0; j < 64; ++j) {
      const float4* kp = (const float4*)&kS[j][seg * 16];
      const float4 ka = kp[0], kb4 = kp[1], kc = kp[2], kd = kp[3];
      const f32x2 K0 = {ka.x, ka.y},  K1 = {ka.z, ka.w};
      const f32x2 K2 = {kb4.x, kb4.y}, K3 = {kb4.z, kb4.w};
      const f32x2 K4 = {kc.x, kc.y},  K5 = {kc.z, kc.w};
      const f32x2 K6 = {kd.x, kd.y},  K7 = {kd.z, kd.w};
      float dt[RPT];
#pragma unroll
      for (int i = 0; i < RPT; ++i) {
        f32x2 a2 = qv[i][0] * K0;
        a2 += qv[i][1] * K1;
        a2 += qv[i][2] * K2;
        a2 += qv[i][3] * K3;
        a2 += qv[i][4] * K4;
        a2 += qv[i][5] * K5;
        a2 += qv[i][6] * K6;
        a2 += qv[i][7] * K7;
        dt[i] = a2[0] + a2[1];
      }
#pragma unroll
      for (int i = 0; i < RPT; ++i) {
        dt[i] += __shfl_xor(dt[i], 1);
        dt[i] += __shfl_xor(dt[i], 2);
      }
      const float cc = (float)(c0 + j);
#pragma unroll
      for (int i = 0; i < RPT; ++i) {
        const float L = dt[i] * sq[i] * cc;
        const float d = L - m[i];
        if (d > 0.f) {
          const float r = expf(-d);
          l[i] = l[i] * r + 1.f;
          m[i] = L;
          const f32x2 r2 = {r, r};
          const float4* vp4 = (const float4*)&vS[j][seg * 16];
          const float4 va = vp4[0], vb4 = vp4[1], vc = vp4[2], vd4 = vp4[3];
          const f32x2 V[8] = {{va.x,va.y},{va.z,va.w},{vb4.x,vb4.y},{vb4.z,vb4.w},
                              {vc.x,vc.y},{vc.z,vc.w},{vd4.x,vd4.y},{vd4.z,vd4.w}};
#pragma unroll
          for (int t = 0; t < 8; ++t) o[i][t] = o[i][t] * r2 + V[t];
        } else if (d > -80.f) {
          const float p = expf(d);
          l[i] += p;
          const f32x2 p2 = {p, p};
          const float4* vp4 = (const float4*)&vS[j][seg * 16];
          const float4 va = vp4[0], vb4 = vp4[1], vc = vp4[2], vd4 = vp4[3];
          const f32x2 V[8] = {{va.x,va.y},{va.z,va.w},{vb4.x,vb4.y},{vb4.z,vb4.w},
                              {vc.x,vc.y},{vc.z,vc.w},{vd4.x,vd4.y},{vd4.z,vd4.w}};
#pragma unroll
          for (int t = 0; t < 8; ++t) o[i][t] += p2 * V[t];
        }
      }
    }
  }

#pragma unroll
  for (int i = 0; i < RPT; ++i) {
    const float inv = 1.f / l[i];
    ushort* op = ctx + (((size_t)b * 2048) + row0 + i) * 1024 + h * 64 + seg * 16;
    uint pk[8];
#pragma unroll
    for (int t2 = 0; t2 < 8; ++t2) {
      const uint lo = OF16 ? (uint)f2h_u(o[i][t2][0] * inv) : (uint)f2b(o[i][t2][0] * inv);
      const uint hi = OF16 ? (uint)f2h_u(o[i][t2][1] * inv) : (uint)f2b(o[i][t2][1] * inv);
      pk[t2] = lo | (hi << 16);
    }
    *(uint4*)(op)     = make_uint4(pk[0], pk[1], pk[2], pk[3]);
    *(uint4*)(op + 8) = make_uint4(pk[4], pk[5], pk[6], pk[7]);
  }
}

// ---------------------------------------------------------------------------
// LayerNorm 1024 cols, bf16 in -> bf16 out (fallback path).
// ---------------------------------------------------------------------------
__global__ __launch_bounds__(256) void ln_k(const ushort* __restrict__ y,
                                            const void* __restrict__ g,
                                            const void* __restrict__ be,
                                            const int* __restrict__ fp,
                                            ushort* __restrict__ out)
{
  const int row = blockIdx.x, tid = threadIdx.x;
  const int f = *fp;
  const ushort* p = y + (size_t)row * 1024;
  float v[4], s = 0.f, s2 = 0.f;
#pragma unroll
  for (int i = 0; i < 4; ++i) {
    const float x = b2f(p[tid + i * 256]);
    v[i] = x; s += x; s2 += x * x;
  }
#pragma unroll
  for (int off = 1; off < 64; off <<= 1) { s += __shfl_xor(s, off); s2 += __shfl_xor(s2, off); }
  __shared__ float red[8];
  const int wave = tid >> 6, lane = tid & 63;
  if (lane == 0) { red[wave] = s; red[4 + wave] = s2; }
  __syncthreads();
  s = red[0] + red[1] + red[2] + red[3];
  s2 = red[4] + red[5] + red[6] + red[7];
  const float mu = s * (1.f / 1024.f);
  const float var = s2 * (1.f / 1024.f) - mu * mu;
  const float rstd = rsqrtf(var + 1e-5f);
  ushort* o = out + (size_t)row * 1024;
#pragma unroll
  for (int i = 0; i < 4; ++i) {
    const int c = tid + i * 256;
    o[c] = f2b((v[i] - mu) * rstd * ldf(g, c, f) + ldf(be, c, f));
  }
}

// ---------------------------------------------------------------------------
// LayerNorm 1024 cols, f16 in -> f16 out (main path).
// ---------------------------------------------------------------------------
__global__ __launch_bounds__(256) void ln_h_k(const _Float16* __restrict__ y,
                                              const void* __restrict__ g,
                                              const void* __restrict__ be,
                                              const int* __restrict__ fp,
                                              _Float16* __restrict__ out)
{
  const int row = blockIdx.x, tid = threadIdx.x;
  const int f = *fp;
  const _Float16* p = y + (size_t)row * 1024;
  float v[4], s = 0.f, s2 = 0.f;
#pragma unroll
  for (int i = 0; i < 4; ++i) {
    const float x = (float)p[tid + i * 256];
    v[i] = x; s += x; s2 += x * x;
  }
#pragma unroll
  for (int off = 1; off < 64; off <<= 1) { s += __shfl_xor(s, off); s2 += __shfl_xor(s2, off); }
  __shared__ float red[8];
  const int wave = tid >> 6, lane = tid & 63;
  if (lane == 0) { red[wave] = s; red[4 + wave] = s2; }
  __syncthreads();
  s = red[0] + red[1] + red[2] + red[3];
  s2 = red[4] + red[5] + red[6] + red[7];
  const float mu = s * (1.f / 1024.f);
  const float var = s2 * (1.f / 1024.f) - mu * mu;
  const float rstd = rsqrtf(var + 1e-5f);
  _Float16* o = out + (size_t)row * 1024;
#pragma unroll
  for (int i = 0; i < 4; ++i) {
    const int c = tid + i * 256;
    o[c] = (_Float16)((v[i] - mu) * rstd * ldf(g, c, f) + ldf(be, c, f));
  }
}

// ---------------------------------------------------------------------------
// Final LayerNorm: fp32 in/out, in place on d_out.
// ---------------------------------------------------------------------------
__global__ __launch_bounds__(256) void ln_f32_k(float* __restrict__ y,
                                                const void* __restrict__ g,
                                                const void* __restrict__ be,
                                                const int* __restrict__ fp)
{
  const int row = blockIdx.x, tid = threadIdx.x;
  const int f = *fp;
  float* p = y + (size_t)row * 1024;
  float v[4], s = 0.f, s2 = 0.f;
#pragma unroll
  for (int i = 0; i < 4; ++i) {
    const float x = p[tid + i * 256];
    v[i] = x; s += x; s2 += x * x;
  }
#pragma unroll
  for (int off = 1; off < 64; off <<= 1) { s += __shfl_xor(s, off); s2 += __shfl_xor(s2, off); }
  __shared__ float red[8];
  const int wave = tid >> 6, lane = tid & 63;
  if (lane == 0) { red[wave] = s; red[4 + wave] = s2; }
  __syncthreads();
  s = red[0] + red[1] + red[2] + red[3];
  s2 = red[4] + red[5] + red[6] + red[7];
  const float mu = s * (1.f / 1024.f);
  const float var = s2 * (1.f / 1024.f) - mu * mu;
  const float rstd = rsqrtf(var + 1e-5f);
#pragma unroll
  for (int i = 0; i < 4; ++i) {
    const int c = tid + i * 256;
    p[c] = (v[i] - mu) * rstd * ldf(g, c, f) + ldf(be, c, f);
  }
}

// ---------------------------------------------------------------------------
extern "C" void kernel_launch(void* const* d_in, const int* in_sizes, int n_in,
                              void* d_out, int out_size, void* d_ws, size_t ws_size,
                              hipStream_t stream)
{
  const void* x  = d_in[0];
  const void* wq = d_in[1];  const void* bq = d_in[2];
  const void* wk = d_in[3];  const void* bk = d_in[4];
  const void* wv = d_in[5];  const void* bv = d_in[6];
  const void* wo = d_in[7];  const void* bo = d_in[8];
  const void* w1 = d_in[9];  const void* b1 = d_in[10];
  const void* w2 = d_in[11]; const void* b2 = d_in[12];
  const void* g1 = d_in[13]; const void* be1 = d_in[14];
  const void* g2 = d_in[15]; const void* be2 = d_in[16];
  float* outp = (float*)d_out;

  const size_t MB = 1048576;
  char* ws = (char*)d_ws;
  int*      flag    = (int*)(ws + 0);
  int*      zeroc   = (int*)(ws + 64);
  unsigned* ovcount = (unsigned*)(ws + 128);
  float*    wtab    = (float*)(ws + 256);

  detect_k<<<dim3(1), dim3(64), 0, stream>>>(x, flag);
  wtab_k<<<dim3(1), dim3(64), 0, stream>>>(wtab, zeroc, ovcount);

  const size_t QS = (size_t)16 * 2048 * 64;   // per-batch q/k/v element count

  if (ws_size >= (size_t)98 * MB) {
    // ---- main path (97.5 MB peak) ----
    float*     qb   = (float*)(ws + 1 * MB);
    float*     kb   = (float*)(ws + 33 * MB);
    ushort*    vb   = (ushort*)(ws + 65 * MB);
    ushort*    ctxh = (ushort*)(ws + 81 * MB);      // f16 bits
    unsigned*  ovlist = (unsigned*)(ws + 97 * MB);  // [131072] u32
    // transient (dead before their regions are overwritten):
    ushort*    W3qT = (ushort*)(ws + 81 * MB);      // 6MB, dead before ctx
    ushort*    W3kT = (ushort*)(ws + 87 * MB);      // 6MB, dead before ctx
    _Float16*  WvT  = (_Float16*)(ws + 93 * MB);    // 2MB, dead before ctx
    _Float16*  WoT  = (_Float16*)(ws + 65 * MB);
    _Float16*  W1T  = (_Float16*)(ws + 67 * MB);
    _Float16*  W2T  = (_Float16*)(ws + 75 * MB);
    _Float16*  y1h  = (_Float16*)(ws + 1 * MB);
    _Float16*  hh   = (_Float16*)(ws + 17 * MB);
    _Float16*  ffc  = (_Float16*)(ws + 33 * MB);

    // weight prep: 3-plane split for wq/wk, f16 transpose for wv
    cvt_w3T_k<<<dim3(32, 32), 256, 0, stream>>>(wq, flag, W3qT);
    cvt_w3T_k<<<dim3(32, 32), 256, 0, stream>>>(wk, flag, W3kT);
    cvt_wT_k<<<dim3(32, 32),  256, 0, stream>>>(wv, flag, WvT, 1024, 1024);

    // q|k fused split-bf16 MFMA projection, v f16 MFMA projection
    sgemm_qk<<<dim3(16, 64), 256, 0, stream>>>(x, flag, W3qT, W3kT,
                                               bq, bk, flag, qb, kb, wtab);
    vgemm_k<<<dim3(8, 64), 256, 0, stream>>>(x, flag, WvT, bv, flag, vb);

    // single-pass MFMA attention (64 rows/block) + key-parallel cleanup
    attn_mfma_k<<<dim3(32, 16, 4), 256, 0, stream>>>(qb, kb, vb, ctxh,
                                                     ovcount, ovlist);
    attn_cleanup2_k<<<dim3(8192), 256, 0, stream>>>(qb, kb, vb, ctxh,
                                                    ovcount, ovlist);

    cvt_wT_k<<<dim3(32, 32),  256, 0, stream>>>(wo, flag, WoT, 1024, 1024);
    cvt_wT_k<<<dim3(128, 32), 256, 0, stream>>>(w1, flag, W1T, 1024, 4096);

    hgemm<4, 128><<<dim3(8, 64), 256, 0, stream>>>((const _Float16*)ctxh, 0, WoT,
                                                   bo, flag, x, flag, nullptr,
                                                   y1h, nullptr, 1024, 1024, 0);
    cvt_wT_k<<<dim3(32, 128), 256, 0, stream>>>(w2, flag, W2T, 4096, 1024);

    ln_h_k<<<dim3(8192), 256, 0, stream>>>(y1h, g1, be1, flag, hh);

    for (int c = 0; c < 2; ++c) {
      hgemm<3, 128><<<dim3(32, 32), 256, 0, stream>>>(hh, c * 4096, W1T,
                                                      b1, flag, nullptr, zeroc, nullptr,
                                                      ffc, nullptr, 4096, 1024, 0);
      hgemm<5, 64><<<dim3(8, 64), 256, 0, stream>>>(ffc, 0, W2T,
                                                    b2, flag, nullptr, zeroc, hh,
                                                    nullptr, outp, 1024, 4096, c * 4096);
    }
    ln_f32_k<<<dim3(8192), 256, 0, stream>>>(outp, g2, be2, flag);
  } else {
    // ---- fallback: original 38 MB layout, bf16 everywhere ----
    float*  qb   = (float*)(ws + 1 * MB);
    float*  kb   = (float*)(ws + 9 * MB);
    ushort* vb   = (ushort*)(ws + 17 * MB);
    ushort* ctxb = (ushort*)(ws + 22 * MB);
    ushort* y1   = (ushort*)(ws + 1 * MB);
    ushort* hbuf = (ushort*)(ws + 22 * MB);
    ushort* ffc  = (ushort*)(ws + 1 * MB);

    for (int b = 0; b < 4; ++b) {
      sgemm<0><<<dim3(16, 32), 256, 0, stream>>>(x, flag, b * 2048, wq, bq, flag,
                                                 nullptr, nullptr, nullptr, qb, wtab,
                                                 1024, 1024, b * 2048);
      sgemm<1><<<dim3(16, 32), 256, 0, stream>>>(x, flag, b * 2048, wk, bk, flag,
                                                 nullptr, nullptr, nullptr, kb, wtab,
                                                 1024, 1024, b * 2048);
      sgemm<2><<<dim3(16, 32), 256, 0, stream>>>(x, flag, b * 2048, wv, bv, flag,
                                                 nullptr, nullptr, vb, nullptr, wtab,
                                                 1024, 1024, b * 2048);
      attn_k<1, 0><<<dim3(32, 16, 1), 256, 0, stream>>>(qb, kb, vb, ctxb, b, 0, 0);
    }

    sgemm<4><<<dim3(16, 128), 256, 0, stream>>>(ctxb, zeroc, 0, wo, bo, flag,
                                                x, flag, y1, nullptr, wtab,
                                                1024, 1024, 0);
    ln_k<<<dim3(8192), 256, 0, stream>>>(y1, g1, be1, flag, hbuf);
    for (int c = 0; c < 4; ++c) {
      sgemm<3><<<dim3(64, 32), 256, 0, stream>>>(hbuf, zeroc, c * 2048, w1, b1, flag,
                                                 nullptr, nullptr, ffc, nullptr, wtab,
                                                 4096, 1024, 0);
      sgemm<5><<<dim3(16, 32), 256, 0, stream>>>(ffc, zeroc, 0, w2, b2, flag,
                                                 hbuf, zeroc, nullptr, outp, wtab,
                                                 1024, 4096, c * 2048);
    }
    ln_f32_k<<<dim3(8192), 256, 0, stream>>>(outp, g2, be2, flag);
  }
}